// Round 1
// baseline (387.510 us; speedup 1.0000x reference)
//
#include <hip/hip_runtime.h>
#include <hip/hip_bf16.h>

// Problem constants
#define BB  32
#define CC  256
#define NN  1024           // H*W
#define NHH 4
#define DKK 64
#define QD  768            // 3 * NH * DK
// softmax in log2 domain: fold (1/sqrt(64)) * log2(e) into q (weights+bias)
#define QSCALE 0.18033688011112042f

typedef __bf16 bf16;
typedef __bf16 bf16x8 __attribute__((ext_vector_type(8)));
typedef float  f32x4  __attribute__((ext_vector_type(4)));

// ---------------------------------------------------------------------------
// Convert weights to bf16. pwt keeps proj_w's native [o][c] layout (that is
// exactly the B^T row-major layout the MFMA B-fragment wants); q-rows get the
// softmax scale folded in. owt = out_w native [c][o] layout (B^T for GEMM2).
__global__ __launch_bounds__(256) void k_prep_w(const float* __restrict__ proj_w,
                                                const float* __restrict__ out_w,
                                                bf16* __restrict__ pwt,
                                                bf16* __restrict__ owt) {
    int i = blockIdx.x * 256 + threadIdx.x;   // grid covers 768*256
    if (i < QD * CC) {
        int o = i / CC;
        float v = proj_w[i];
        if ((o % 192) < DKK) v *= QSCALE;     // q rows
        pwt[i] = (bf16)v;
    }
    if (i < CC * CC) {
        owt[i] = (bf16)out_w[i];
    }
}

// ---------------------------------------------------------------------------
// x [B][C][N] f32  ->  xs [B*N][C] bf16   (LDS-tiled transpose, 64x64 tiles)
__global__ __launch_bounds__(256) void k_transpose_x(const float* __restrict__ x,
                                                     bf16* __restrict__ xs) {
    int bid = blockIdx.x;                 // B * (C/64) * (N/64) = 2048
    int nt = bid & 15;
    int ct = (bid >> 4) & 3;
    int b  = bid >> 6;
    __shared__ float lds[64][65];
    int t = threadIdx.x;
    const float* xp = x + ((size_t)b * CC + ct * 64) * NN + nt * 64;
#pragma unroll
    for (int rep = 0; rep < 16; ++rep) {
        int idx = rep * 256 + t;
        int c = idx >> 6, n = idx & 63;
        lds[c][n] = xp[(size_t)c * NN + n];          // coalesced over n
    }
    __syncthreads();
    bf16* xo = xs + ((size_t)b * NN + nt * 64) * CC + ct * 64;
#pragma unroll
    for (int rep = 0; rep < 16; ++rep) {
        int idx = rep * 256 + t;
        int c = idx & 63, n = idx >> 6;
        xo[(size_t)n * CC + c] = (bf16)lds[c][n];    // coalesced over c
    }
}

// ---------------------------------------------------------------------------
// QKV GEMM: qkv[row][col] = xs[row][:] . pwt[col][:] + bias  (M=32768,K=256,N=768)
// 64x64 tile, 4 waves (2x2), wave = 32x32 via 2x2 16x16x32 MFMA fragments.
__global__ __launch_bounds__(256) void k_gemm_qkv(const bf16* __restrict__ A,
                                                  const bf16* __restrict__ Bw,
                                                  const float* __restrict__ bias,
                                                  bf16* __restrict__ Cout) {
    int bid = blockIdx.x;                 // (32768/64) * (768/64) = 6144
    int ntile = bid % 12;
    int mtile = bid / 12;
    int wave = threadIdx.x >> 6, lane = threadIdx.x & 63;
    int wm = wave >> 1, wn = wave & 1;
    int lr = lane & 15, lg = lane >> 4;
    int row0 = mtile * 64 + wm * 32;
    int col0 = ntile * 64 + wn * 32;
    f32x4 acc[2][2] = {};
    for (int k0 = 0; k0 < CC; k0 += 32) {
        bf16x8 af[2], bfr[2];
#pragma unroll
        for (int mt = 0; mt < 2; ++mt)
            af[mt] = *reinterpret_cast<const bf16x8*>(
                A + (size_t)(row0 + mt * 16 + lr) * CC + k0 + 8 * lg);
#pragma unroll
        for (int nt = 0; nt < 2; ++nt)
            bfr[nt] = *reinterpret_cast<const bf16x8*>(
                Bw + (size_t)(col0 + nt * 16 + lr) * CC + k0 + 8 * lg);
#pragma unroll
        for (int mt = 0; mt < 2; ++mt)
#pragma unroll
            for (int nt = 0; nt < 2; ++nt)
                acc[mt][nt] = __builtin_amdgcn_mfma_f32_16x16x32_bf16(
                    af[mt], bfr[nt], acc[mt][nt], 0, 0, 0);
    }
#pragma unroll
    for (int mt = 0; mt < 2; ++mt)
#pragma unroll
        for (int nt = 0; nt < 2; ++nt)
#pragma unroll
            for (int r = 0; r < 4; ++r) {
                int row = row0 + mt * 16 + lg * 4 + r;
                int col = col0 + nt * 16 + lr;
                float bv = bias[col];
                if ((col % 192) < DKK) bv *= QSCALE;
                Cout[(size_t)row * QD + col] = (bf16)(acc[mt][nt][r] + bv);
            }
}

// ---------------------------------------------------------------------------
// V slice of qkv -> vt [B][NH][DK][N] bf16 (so PV B-fragments are contiguous)
__global__ __launch_bounds__(256) void k_transpose_v(const bf16* __restrict__ qkv,
                                                     bf16* __restrict__ vt) {
    int bid = blockIdx.x;                 // B * NH * (N/64) = 2048
    int nt = bid & 15;
    int h  = (bid >> 4) & 3;
    int b  = bid >> 6;
    __shared__ bf16 lds[64][65];
    int t = threadIdx.x;
#pragma unroll
    for (int rep = 0; rep < 16; ++rep) {
        int idx = rep * 256 + t;
        int n = idx >> 6, d = idx & 63;
        lds[n][d] = qkv[(size_t)(b * NN + nt * 64 + n) * QD + h * 192 + 128 + d];
    }
    __syncthreads();
#pragma unroll
    for (int rep = 0; rep < 16; ++rep) {
        int idx = rep * 256 + t;
        int d = idx >> 6, n = idx & 63;
        vt[((size_t)(b * NHH + h) * DKK + d) * NN + nt * 64 + n] = lds[n][d];
    }
}

// ---------------------------------------------------------------------------
// Flash attention. 1 wave = 16 q-rows; block = 4 waves = 64 q-rows of one (b,h).
// Scores already carry scale*log2e (folded into q) -> exp2 softmax.
__global__ __launch_bounds__(256) void k_attn(const bf16* __restrict__ qkv,
                                              const bf16* __restrict__ vt,
                                              bf16* __restrict__ ctx) {
    int bid = blockIdx.x;                 // B * NH * (N/64) = 2048
    int qt = bid & 15;
    int h  = (bid >> 4) & 3;
    int b  = bid >> 6;
    int wave = threadIdx.x >> 6, lane = threadIdx.x & 63;
    int lr = lane & 15, lg = lane >> 4;
    int qbase = qt * 64 + wave * 16;
    __shared__ bf16 plds[4][16][32];      // per-wave P tile, XOR-swizzled cols

    const bf16* qkb = qkv + (size_t)b * NN * QD;
    const bf16* qrow = qkb + (size_t)(qbase + lr) * QD + h * 192;
    bf16x8 qa0 = *reinterpret_cast<const bf16x8*>(qrow + 8 * lg);
    bf16x8 qa1 = *reinterpret_cast<const bf16x8*>(qrow + 32 + 8 * lg);
    const bf16* vb = vt + (size_t)(b * NHH + h) * DKK * NN;

    f32x4 acc[4] = {};
    float m_r[4] = {-1e30f, -1e30f, -1e30f, -1e30f};
    float l_r[4] = {0.f, 0.f, 0.f, 0.f};

    for (int kb = 0; kb < NN; kb += 32) {
        f32x4 s[2];
#pragma unroll
        for (int t2 = 0; t2 < 2; ++t2) {
            const bf16* krow = qkb + (size_t)(kb + t2 * 16 + lr) * QD + h * 192 + 64;
            bf16x8 kf0 = *reinterpret_cast<const bf16x8*>(krow + 8 * lg);
            bf16x8 kf1 = *reinterpret_cast<const bf16x8*>(krow + 32 + 8 * lg);
            f32x4 z = {};
            z = __builtin_amdgcn_mfma_f32_16x16x32_bf16(qa0, kf0, z, 0, 0, 0);
            z = __builtin_amdgcn_mfma_f32_16x16x32_bf16(qa1, kf1, z, 0, 0, 0);
            s[t2] = z;
        }
        // online softmax; s[t2][r] = S[q=lg*4+r][key=kb+t2*16+lr] (log2 domain)
#pragma unroll
        for (int r = 0; r < 4; ++r) {
            float mx = fmaxf(s[0][r], s[1][r]);
            mx = fmaxf(mx, __shfl_xor(mx, 1));
            mx = fmaxf(mx, __shfl_xor(mx, 2));
            mx = fmaxf(mx, __shfl_xor(mx, 4));
            mx = fmaxf(mx, __shfl_xor(mx, 8));
            float mn = fmaxf(m_r[r], mx);
            float corr = __builtin_amdgcn_exp2f(m_r[r] - mn);
            float p0 = __builtin_amdgcn_exp2f(s[0][r] - mn);
            float p1 = __builtin_amdgcn_exp2f(s[1][r] - mn);
            float ps = p0 + p1;
            ps += __shfl_xor(ps, 1);
            ps += __shfl_xor(ps, 2);
            ps += __shfl_xor(ps, 4);
            ps += __shfl_xor(ps, 8);
            l_r[r] = l_r[r] * corr + ps;
            m_r[r] = mn;
#pragma unroll
            for (int t = 0; t < 4; ++t) acc[t][r] *= corr;
            int q = lg * 4 + r;
            int sw = r << 3;              // (q&3)<<3 == r<<3
            plds[wave][q][lr ^ sw] = (bf16)p0;
            plds[wave][q][(16 + lr) ^ sw] = (bf16)p1;
        }
        // P A-fragment: row=lr, k=8*lg..+7 (undo swizzle with row's mask)
        bf16x8 pa = *reinterpret_cast<const bf16x8*>(
            &plds[wave][lr][(8 * lg) ^ ((lr & 3) << 3)]);
#pragma unroll
        for (int t = 0; t < 4; ++t) {
            bf16x8 vf = *reinterpret_cast<const bf16x8*>(
                vb + (size_t)(t * 16 + lr) * NN + kb + 8 * lg);
            acc[t] = __builtin_amdgcn_mfma_f32_16x16x32_bf16(pa, vf, acc[t], 0, 0, 0);
        }
    }
    bf16* cb = ctx + ((size_t)(b * NN + qbase)) * 256 + h * 64;
#pragma unroll
    for (int r = 0; r < 4; ++r) {
        float inv = 1.0f / l_r[r];
#pragma unroll
        for (int t = 0; t < 4; ++t)
            cb[(size_t)(lg * 4 + r) * 256 + t * 16 + lr] = (bf16)(acc[t][r] * inv);
    }
}

// ---------------------------------------------------------------------------
// Out GEMM + bias + residual, transposed epilogue to [B][C][N] f32.
__global__ __launch_bounds__(256) void k_gemm_out(const bf16* __restrict__ A,
                                                  const bf16* __restrict__ Bw,
                                                  const float* __restrict__ bias,
                                                  const float* __restrict__ x,
                                                  float* __restrict__ out) {
    int bid = blockIdx.x;                 // (32768/64) * (256/64) = 2048
    int ntile = bid & 3;
    int mtile = bid >> 2;
    int wave = threadIdx.x >> 6, lane = threadIdx.x & 63;
    int wm = wave >> 1, wn = wave & 1;
    int lr = lane & 15, lg = lane >> 4;
    int row0 = mtile * 64 + wm * 32;
    int col0 = ntile * 64 + wn * 32;
    f32x4 acc[2][2] = {};
    for (int k0 = 0; k0 < CC; k0 += 32) {
        bf16x8 af[2], bfr[2];
#pragma unroll
        for (int mt = 0; mt < 2; ++mt)
            af[mt] = *reinterpret_cast<const bf16x8*>(
                A + (size_t)(row0 + mt * 16 + lr) * CC + k0 + 8 * lg);
#pragma unroll
        for (int nt = 0; nt < 2; ++nt)
            bfr[nt] = *reinterpret_cast<const bf16x8*>(
                Bw + (size_t)(col0 + nt * 16 + lr) * CC + k0 + 8 * lg);
#pragma unroll
        for (int mt = 0; mt < 2; ++mt)
#pragma unroll
            for (int nt = 0; nt < 2; ++nt)
                acc[mt][nt] = __builtin_amdgcn_mfma_f32_16x16x32_bf16(
                    af[mt], bfr[nt], acc[mt][nt], 0, 0, 0);
    }
    __shared__ float lds[64][65];
#pragma unroll
    for (int mt = 0; mt < 2; ++mt)
#pragma unroll
        for (int nt = 0; nt < 2; ++nt)
#pragma unroll
            for (int r = 0; r < 4; ++r)
                lds[wm * 32 + mt * 16 + lg * 4 + r][wn * 32 + nt * 16 + lr] =
                    acc[mt][nt][r];
    __syncthreads();
    int b = mtile >> 4;
    int nbase = (mtile & 15) * 64;
#pragma unroll
    for (int rep = 0; rep < 16; ++rep) {
        int idx = rep * 256 + threadIdx.x;
        int nl = idx & 63, cl = idx >> 6;
        int c = ntile * 64 + cl;
        size_t o = ((size_t)b * CC + c) * NN + nbase + nl;
        out[o] = lds[nl][cl] + bias[c] + x[o];   // coalesced read+write over n
    }
}

// ---------------------------------------------------------------------------
extern "C" void kernel_launch(void* const* d_in, const int* in_sizes, int n_in,
                              void* d_out, int out_size, void* d_ws, size_t ws_size,
                              hipStream_t stream) {
    const float* x      = (const float*)d_in[0];
    const float* proj_w = (const float*)d_in[1];
    const float* proj_b = (const float*)d_in[2];
    const float* out_w  = (const float*)d_in[3];
    const float* out_b  = (const float*)d_in[4];
    float* out = (float*)d_out;

    // workspace layout (bf16 elements); ctx aliases xs (xs dead after QKV GEMM)
    bf16* xs  = (bf16*)d_ws;                       // 32768*256
    bf16* qkv = xs + (size_t)32768 * 256;          // 32768*768
    bf16* vt  = qkv + (size_t)32768 * 768;         // 32*4*64*1024
    bf16* pwt = vt + (size_t)8388608;              // 768*256
    bf16* owt = pwt + (size_t)768 * 256;           // 256*256
    bf16* ctx = xs;

    k_prep_w     <<<dim3(768),  dim3(256), 0, stream>>>(proj_w, out_w, pwt, owt);
    k_transpose_x<<<dim3(2048), dim3(256), 0, stream>>>(x, xs);
    k_gemm_qkv   <<<dim3(6144), dim3(256), 0, stream>>>(xs, pwt, proj_b, qkv);
    k_transpose_v<<<dim3(2048), dim3(256), 0, stream>>>(qkv, vt);
    k_attn       <<<dim3(2048), dim3(256), 0, stream>>>(qkv, vt, ctx);
    k_gemm_out   <<<dim3(2048), dim3(256), 0, stream>>>(ctx, owt, out_b, x, out);
}

// Round 2
// 276.200 us; speedup vs baseline: 1.4030x; 1.4030x over previous
//
#include <hip/hip_runtime.h>
#include <hip/hip_bf16.h>

// Problem constants
#define BB  32
#define CC  256
#define NN  1024           // H*W
#define NHH 4
#define DKK 64
#define QD  768            // 3 * NH * DK
// softmax in log2 domain: fold (1/sqrt(64)) * log2(e) into q (weights+bias)
#define QSCALE 0.18033688011112042f

typedef __bf16 bf16;
typedef __bf16 bf16x8 __attribute__((ext_vector_type(8)));
typedef float  f32x4  __attribute__((ext_vector_type(4)));
typedef float  f32x16 __attribute__((ext_vector_type(16)));

// ---------------------------------------------------------------------------
// Convert weights to bf16. pwt keeps proj_w's native [o][c] layout (that is
// exactly the B^T row-major layout the MFMA B-fragment wants); q-rows get the
// softmax scale folded in. owt = out_w native [c][o] layout (B^T for GEMM2).
__global__ __launch_bounds__(256) void k_prep_w(const float* __restrict__ proj_w,
                                                const float* __restrict__ out_w,
                                                bf16* __restrict__ pwt,
                                                bf16* __restrict__ owt) {
    int i = blockIdx.x * 256 + threadIdx.x;   // grid covers 768*256
    if (i < QD * CC) {
        int o = i / CC;
        float v = proj_w[i];
        if ((o % 192) < DKK) v *= QSCALE;     // q rows
        pwt[i] = (bf16)v;
    }
    if (i < CC * CC) {
        owt[i] = (bf16)out_w[i];
    }
}

// ---------------------------------------------------------------------------
// x [B][C][N] f32  ->  xs [B*N][C] bf16   (LDS-tiled transpose, 64x64 tiles)
__global__ __launch_bounds__(256) void k_transpose_x(const float* __restrict__ x,
                                                     bf16* __restrict__ xs) {
    int bid = blockIdx.x;                 // B * (C/64) * (N/64) = 2048
    int nt = bid & 15;
    int ct = (bid >> 4) & 3;
    int b  = bid >> 6;
    __shared__ float lds[64][65];
    int t = threadIdx.x;
    const float* xp = x + ((size_t)b * CC + ct * 64) * NN + nt * 64;
#pragma unroll
    for (int rep = 0; rep < 16; ++rep) {
        int idx = rep * 256 + t;
        int c = idx >> 6, n = idx & 63;
        lds[c][n] = xp[(size_t)c * NN + n];          // coalesced over n
    }
    __syncthreads();
    bf16* xo = xs + ((size_t)b * NN + nt * 64) * CC + ct * 64;
#pragma unroll
    for (int rep = 0; rep < 16; ++rep) {
        int idx = rep * 256 + t;
        int c = idx & 63, n = idx >> 6;
        xo[(size_t)n * CC + c] = (bf16)lds[c][n];    // coalesced over c
    }
}

// ---------------------------------------------------------------------------
// QKV GEMM: qkv[row][col] = xs[row][:] . pwt[col][:] + bias  (M=32768,K=256,N=768)
// 64x64 tile, 4 waves (2x2), wave = 32x32 via 2x2 16x16x32 MFMA fragments.
__global__ __launch_bounds__(256) void k_gemm_qkv(const bf16* __restrict__ A,
                                                  const bf16* __restrict__ Bw,
                                                  const float* __restrict__ bias,
                                                  bf16* __restrict__ Cout) {
    int bid = blockIdx.x;                 // (32768/64) * (768/64) = 6144
    int ntile = bid % 12;
    int mtile = bid / 12;
    int wave = threadIdx.x >> 6, lane = threadIdx.x & 63;
    int wm = wave >> 1, wn = wave & 1;
    int lr = lane & 15, lg = lane >> 4;
    int row0 = mtile * 64 + wm * 32;
    int col0 = ntile * 64 + wn * 32;
    f32x4 acc[2][2] = {};
    for (int k0 = 0; k0 < CC; k0 += 32) {
        bf16x8 af[2], bfr[2];
#pragma unroll
        for (int mt = 0; mt < 2; ++mt)
            af[mt] = *reinterpret_cast<const bf16x8*>(
                A + (size_t)(row0 + mt * 16 + lr) * CC + k0 + 8 * lg);
#pragma unroll
        for (int nt = 0; nt < 2; ++nt)
            bfr[nt] = *reinterpret_cast<const bf16x8*>(
                Bw + (size_t)(col0 + nt * 16 + lr) * CC + k0 + 8 * lg);
#pragma unroll
        for (int mt = 0; mt < 2; ++mt)
#pragma unroll
            for (int nt = 0; nt < 2; ++nt)
                acc[mt][nt] = __builtin_amdgcn_mfma_f32_16x16x32_bf16(
                    af[mt], bfr[nt], acc[mt][nt], 0, 0, 0);
    }
#pragma unroll
    for (int mt = 0; mt < 2; ++mt)
#pragma unroll
        for (int nt = 0; nt < 2; ++nt)
#pragma unroll
            for (int r = 0; r < 4; ++r) {
                int row = row0 + mt * 16 + lg * 4 + r;
                int col = col0 + nt * 16 + lr;
                float bv = bias[col];
                if ((col % 192) < DKK) bv *= QSCALE;
                Cout[(size_t)row * QD + col] = (bf16)(acc[mt][nt][r] + bv);
            }
}

// ---------------------------------------------------------------------------
// V slice of qkv -> vt [B][NH][DK][N] bf16 (so PV A-fragments are contiguous)
__global__ __launch_bounds__(256) void k_transpose_v(const bf16* __restrict__ qkv,
                                                     bf16* __restrict__ vt) {
    int bid = blockIdx.x;                 // B * NH * (N/64) = 2048
    int nt = bid & 15;
    int h  = (bid >> 4) & 3;
    int b  = bid >> 6;
    __shared__ bf16 lds[64][65];
    int t = threadIdx.x;
#pragma unroll
    for (int rep = 0; rep < 16; ++rep) {
        int idx = rep * 256 + t;
        int n = idx >> 6, d = idx & 63;
        lds[n][d] = qkv[(size_t)(b * NN + nt * 64 + n) * QD + h * 192 + 128 + d];
    }
    __syncthreads();
#pragma unroll
    for (int rep = 0; rep < 16; ++rep) {
        int idx = rep * 256 + t;
        int d = idx >> 6, n = idx & 63;
        vt[((size_t)(b * NHH + h) * DKK + d) * NN + nt * 64 + n] = lds[n][d];
    }
}

// ---------------------------------------------------------------------------
// Flash attention, fully-swapped 32x32 MFMA structure (m214-style):
//   S^T[key][q] = mfma(A=K, B=Q)  -> lane holds 16 keys for q = lane&31
//   softmax entirely in-register (permlane32_swap for the cross-half reduce)
//   P -> B-frag via cvt_pk_bf16 + permlane32_swap (T12)
//   O^T[d][q]  = mfma(A=V^T, B=P) -> rescale/normalize factors live in-lane
// 1 wave = 32 q-rows; block = 4 waves = 128 q-rows of one (b,h).
__global__ __launch_bounds__(256) void k_attn(const bf16* __restrict__ qkv,
                                              const bf16* __restrict__ vt,
                                              bf16* __restrict__ ctx) {
    int bid = blockIdx.x;                 // B * NH * (N/128) = 1024
    int qt = bid & 7;
    int h  = (bid >> 3) & 3;
    int b  = bid >> 5;
    int wave = threadIdx.x >> 6, lane = threadIdx.x & 63;
    int lq = lane & 31, hi = lane >> 5;
    int q0 = qt * 128 + wave * 32;

    const bf16* qkb = qkv + (size_t)b * NN * QD;
    // Q B-frag: lane holds col q = q0+lq, k-elems d = 16*dk + 8*hi + j
    const bf16* qrow = qkb + (size_t)(q0 + lq) * QD + h * 192 + 8 * hi;
    bf16x8 qf[4];
#pragma unroll
    for (int dk = 0; dk < 4; ++dk)
        qf[dk] = *reinterpret_cast<const bf16x8*>(qrow + 16 * dk);

    // K A-frag base: row key = kb+lq, k-elems d = 16*dk + 8*hi + j
    const bf16* kp = qkb + h * 192 + 64 + (size_t)lq * QD + 8 * hi;
    // V^T A-frag base: row d = 32*t + lq, k-elems key = kb + 16*kk + 8*hi + j
    const bf16* vp = vt + (size_t)(b * NHH + h) * DKK * NN + (size_t)lq * NN + 8 * hi;

    f32x16 acc0 = {}, acc1 = {};          // O^T: rows d (d<32 / d>=32), col q=lq
    float m = -1e30f, l = 0.f;            // per-lane (q = lq); l is half-partial

    for (int kb = 0; kb < NN; kb += 32) {
        const bf16* kpp = kp + (size_t)kb * QD;
        f32x16 s = {};
#pragma unroll
        for (int dk = 0; dk < 4; ++dk) {
            bf16x8 kf = *reinterpret_cast<const bf16x8*>(kpp + 16 * dk);
            s = __builtin_amdgcn_mfma_f32_32x32x16_bf16(kf, qf[dk], s, 0, 0, 0);
        }
        // s[r] = S^T[key = (r&3)+8*(r>>2)+4*hi + kb][q = lq]   (log2 domain)
        float pm = s[0];
#pragma unroll
        for (int i = 1; i < 16; ++i) pm = fmaxf(pm, s[i]);
        {   // combine with the other 16 keys (lane ^ 32)
            float a = pm, b2 = pm;
            asm("v_permlane32_swap_b32 %0, %1" : "+v"(a), "+v"(b2));
            pm = fmaxf(a, b2);
        }
        // defer-max (T13): rescale only when max grew by > 8 (P bounded by 256)
        if (__any(pm > m + 8.f)) {
            float nm = fmaxf(m, pm);
            float corr = __builtin_amdgcn_exp2f(m - nm);
            l *= corr;
            acc0 *= corr;
            acc1 *= corr;
            m = nm;
        }
        float p[16];
        float ls = 0.f;
#pragma unroll
        for (int i = 0; i < 16; ++i) {
            p[i] = __builtin_amdgcn_exp2f(s[i] - m);
            ls += p[i];
        }
        l += ls;
        // T12: pack P into the two PV B-frags (keys 0-15, keys 16-31).
        // word j of frag must hold keys {16*kk + 8*hi + 2j, +1}.
        // cvtpk(p0,p1):  hi=0 {k0,k1},  hi=1 {k4,k5}
        // cvtpk(p4,p5):  hi=0 {k8,k9},  hi=1 {k12,k13}
        // permlane32_swap of the pair -> word0 {k0k1|k8k9}, word2 {k4k5|k12k13}
        unsigned w[8];
#pragma unroll
        for (int g = 0; g < 2; ++g) {
#pragma unroll
            for (int j = 0; j < 4; ++j) {
                unsigned t;
                asm("v_cvt_pk_bf16_f32 %0, %1, %2"
                    : "=v"(t) : "v"(p[8 * g + 2 * j]), "v"(p[8 * g + 2 * j + 1]));
                w[4 * g + j] = t;
            }
            asm("v_permlane32_swap_b32 %0, %1" : "+v"(w[4 * g + 0]), "+v"(w[4 * g + 2]));
            asm("v_permlane32_swap_b32 %0, %1" : "+v"(w[4 * g + 1]), "+v"(w[4 * g + 3]));
        }
        union { unsigned u[4]; bf16x8 v; } pu0, pu1;
#pragma unroll
        for (int j = 0; j < 4; ++j) { pu0.u[j] = w[j]; pu1.u[j] = w[4 + j]; }

        const bf16* vpp = vp + kb;
        bf16x8 vf;
        vf = *reinterpret_cast<const bf16x8*>(vpp);
        acc0 = __builtin_amdgcn_mfma_f32_32x32x16_bf16(vf, pu0.v, acc0, 0, 0, 0);
        vf = *reinterpret_cast<const bf16x8*>(vpp + 16);
        acc0 = __builtin_amdgcn_mfma_f32_32x32x16_bf16(vf, pu1.v, acc0, 0, 0, 0);
        vf = *reinterpret_cast<const bf16x8*>(vpp + 32 * NN);
        acc1 = __builtin_amdgcn_mfma_f32_32x32x16_bf16(vf, pu0.v, acc1, 0, 0, 0);
        vf = *reinterpret_cast<const bf16x8*>(vpp + 32 * NN + 16);
        acc1 = __builtin_amdgcn_mfma_f32_32x32x16_bf16(vf, pu1.v, acc1, 0, 0, 0);
    }

    // combine the two key-half partial sums of l, normalize (all in-lane: q=lq)
    {
        float a = l, b2 = l;
        asm("v_permlane32_swap_b32 %0, %1" : "+v"(a), "+v"(b2));
        l = a + b2;
    }
    float inv = 1.0f / l;

    // O^T -> O transpose via per-wave LDS tile (pitch 68 bf16: 2-way-free writes,
    // 8B-aligned b64 reads), then coalesced 16B global stores.
    __shared__ bf16 tl[4][32][68];
#pragma unroll
    for (int r = 0; r < 16; ++r) {
        int d = (r & 3) + 8 * (r >> 2) + 4 * hi;
        tl[wave][lq][d]      = (bf16)(acc0[r] * inv);
        tl[wave][lq][d + 32] = (bf16)(acc1[r] * inv);
    }
    __syncthreads();
    bf16* cb = ctx + ((size_t)(b * NN + q0)) * 256 + h * 64;
#pragma unroll
    for (int r = 0; r < 4; ++r) {
        int q = 8 * r + (lane >> 3);
        int d0 = (lane & 7) * 8;
        uint2 lo  = *reinterpret_cast<const uint2*>(&tl[wave][q][d0]);
        uint2 hi2 = *reinterpret_cast<const uint2*>(&tl[wave][q][d0 + 4]);
        uint4 o4 = make_uint4(lo.x, lo.y, hi2.x, hi2.y);
        *reinterpret_cast<uint4*>(cb + (size_t)q * 256 + d0) = o4;
    }
}

// ---------------------------------------------------------------------------
// Out GEMM + bias + residual, transposed epilogue to [B][C][N] f32.
__global__ __launch_bounds__(256) void k_gemm_out(const bf16* __restrict__ A,
                                                  const bf16* __restrict__ Bw,
                                                  const float* __restrict__ bias,
                                                  const float* __restrict__ x,
                                                  float* __restrict__ out) {
    int bid = blockIdx.x;                 // (32768/64) * (256/64) = 2048
    int ntile = bid & 3;
    int mtile = bid >> 2;
    int wave = threadIdx.x >> 6, lane = threadIdx.x & 63;
    int wm = wave >> 1, wn = wave & 1;
    int lr = lane & 15, lg = lane >> 4;
    int row0 = mtile * 64 + wm * 32;
    int col0 = ntile * 64 + wn * 32;
    f32x4 acc[2][2] = {};
    for (int k0 = 0; k0 < CC; k0 += 32) {
        bf16x8 af[2], bfr[2];
#pragma unroll
        for (int mt = 0; mt < 2; ++mt)
            af[mt] = *reinterpret_cast<const bf16x8*>(
                A + (size_t)(row0 + mt * 16 + lr) * CC + k0 + 8 * lg);
#pragma unroll
        for (int nt = 0; nt < 2; ++nt)
            bfr[nt] = *reinterpret_cast<const bf16x8*>(
                Bw + (size_t)(col0 + nt * 16 + lr) * CC + k0 + 8 * lg);
#pragma unroll
        for (int mt = 0; mt < 2; ++mt)
#pragma unroll
            for (int nt = 0; nt < 2; ++nt)
                acc[mt][nt] = __builtin_amdgcn_mfma_f32_16x16x32_bf16(
                    af[mt], bfr[nt], acc[mt][nt], 0, 0, 0);
    }
    __shared__ float lds[64][65];
#pragma unroll
    for (int mt = 0; mt < 2; ++mt)
#pragma unroll
        for (int nt = 0; nt < 2; ++nt)
#pragma unroll
            for (int r = 0; r < 4; ++r)
                lds[wm * 32 + mt * 16 + lg * 4 + r][wn * 32 + nt * 16 + lr] =
                    acc[mt][nt][r];
    __syncthreads();
    int b = mtile >> 4;
    int nbase = (mtile & 15) * 64;
#pragma unroll
    for (int rep = 0; rep < 16; ++rep) {
        int idx = rep * 256 + threadIdx.x;
        int nl = idx & 63, cl = idx >> 6;
        int c = ntile * 64 + cl;
        size_t o = ((size_t)b * CC + c) * NN + nbase + nl;
        out[o] = lds[nl][cl] + bias[c] + x[o];   // coalesced read+write over n
    }
}

// ---------------------------------------------------------------------------
extern "C" void kernel_launch(void* const* d_in, const int* in_sizes, int n_in,
                              void* d_out, int out_size, void* d_ws, size_t ws_size,
                              hipStream_t stream) {
    const float* x      = (const float*)d_in[0];
    const float* proj_w = (const float*)d_in[1];
    const float* proj_b = (const float*)d_in[2];
    const float* out_w  = (const float*)d_in[3];
    const float* out_b  = (const float*)d_in[4];
    float* out = (float*)d_out;

    // workspace layout (bf16 elements); ctx aliases xs (xs dead after QKV GEMM)
    bf16* xs  = (bf16*)d_ws;                       // 32768*256
    bf16* qkv = xs + (size_t)32768 * 256;          // 32768*768
    bf16* vt  = qkv + (size_t)32768 * 768;         // 32*4*64*1024
    bf16* pwt = vt + (size_t)8388608;              // 768*256
    bf16* owt = pwt + (size_t)768 * 256;           // 256*256
    bf16* ctx = xs;

    k_prep_w     <<<dim3(768),  dim3(256), 0, stream>>>(proj_w, out_w, pwt, owt);
    k_transpose_x<<<dim3(2048), dim3(256), 0, stream>>>(x, xs);
    k_gemm_qkv   <<<dim3(6144), dim3(256), 0, stream>>>(xs, pwt, proj_b, qkv);
    k_transpose_v<<<dim3(2048), dim3(256), 0, stream>>>(qkv, vt);
    k_attn       <<<dim3(1024), dim3(256), 0, stream>>>(qkv, vt, ctx);
    k_gemm_out   <<<dim3(2048), dim3(256), 0, stream>>>(ctx, owt, out_b, x, out);
}

// Round 3
// 268.638 us; speedup vs baseline: 1.4425x; 1.0281x over previous
//
#include <hip/hip_runtime.h>
#include <hip/hip_bf16.h>

// Problem constants
#define BB  32
#define CC  256
#define NN  1024           // H*W
#define NHH 4
#define DKK 64
#define QD  768            // 3 * NH * DK
// softmax in log2 domain: fold (1/sqrt(64)) * log2(e) into q (weights+bias)
#define QSCALE 0.18033688011112042f

typedef __bf16 bf16;
typedef __bf16 bf16x8 __attribute__((ext_vector_type(8)));
typedef float  f32x4  __attribute__((ext_vector_type(4)));
typedef float  f32x16 __attribute__((ext_vector_type(16)));

// ---------------------------------------------------------------------------
// Convert weights to bf16. pwt keeps proj_w's native [o][c] layout (that is
// exactly the B^T row-major layout the MFMA B-fragment wants); q-rows get the
// softmax scale folded in. owt = out_w native [c][o] layout (B^T for GEMM2).
__global__ __launch_bounds__(256) void k_prep_w(const float* __restrict__ proj_w,
                                                const float* __restrict__ out_w,
                                                bf16* __restrict__ pwt,
                                                bf16* __restrict__ owt) {
    int i = blockIdx.x * 256 + threadIdx.x;   // grid covers 768*256
    if (i < QD * CC) {
        int o = i / CC;
        float v = proj_w[i];
        if ((o % 192) < DKK) v *= QSCALE;     // q rows
        pwt[i] = (bf16)v;
    }
    if (i < CC * CC) {
        owt[i] = (bf16)out_w[i];
    }
}

// ---------------------------------------------------------------------------
// x [B][C][N] f32  ->  xs [B*N][C] bf16   (LDS-tiled transpose, 64x64 tiles)
__global__ __launch_bounds__(256) void k_transpose_x(const float* __restrict__ x,
                                                     bf16* __restrict__ xs) {
    int bid = blockIdx.x;                 // B * (C/64) * (N/64) = 2048
    int nt = bid & 15;
    int ct = (bid >> 4) & 3;
    int b  = bid >> 6;
    __shared__ float lds[64][65];
    int t = threadIdx.x;
    const float* xp = x + ((size_t)b * CC + ct * 64) * NN + nt * 64;
#pragma unroll
    for (int rep = 0; rep < 16; ++rep) {
        int idx = rep * 256 + t;
        int c = idx >> 6, n = idx & 63;
        lds[c][n] = xp[(size_t)c * NN + n];          // coalesced over n
    }
    __syncthreads();
    bf16* xo = xs + ((size_t)b * NN + nt * 64) * CC + ct * 64;
#pragma unroll
    for (int rep = 0; rep < 16; ++rep) {
        int idx = rep * 256 + t;
        int c = idx & 63, n = idx >> 6;
        xo[(size_t)n * CC + c] = (bf16)lds[c][n];    // coalesced over c
    }
}

// ---------------------------------------------------------------------------
// QKV GEMM: qkv[row][col] = xs[row][:] . pwt[col][:] + bias  (M=32768,K=256,N=768)
// 64x64 tile, 4 waves (2x2), wave = 32x32 via 2x2 16x16x32 MFMA fragments.
__global__ __launch_bounds__(256, 4) void k_gemm_qkv(const bf16* __restrict__ A,
                                                     const bf16* __restrict__ Bw,
                                                     const float* __restrict__ bias,
                                                     bf16* __restrict__ Cout) {
    int bid = blockIdx.x;                 // (32768/64) * (768/64) = 6144
    int ntile = bid % 12;
    int mtile = bid / 12;
    int wave = threadIdx.x >> 6, lane = threadIdx.x & 63;
    int wm = wave >> 1, wn = wave & 1;
    int lr = lane & 15, lg = lane >> 4;
    int row0 = mtile * 64 + wm * 32;
    int col0 = ntile * 64 + wn * 32;
    f32x4 acc[2][2] = {};
    for (int k0 = 0; k0 < CC; k0 += 32) {
        bf16x8 af[2], bfr[2];
#pragma unroll
        for (int mt = 0; mt < 2; ++mt)
            af[mt] = *reinterpret_cast<const bf16x8*>(
                A + (size_t)(row0 + mt * 16 + lr) * CC + k0 + 8 * lg);
#pragma unroll
        for (int nt = 0; nt < 2; ++nt)
            bfr[nt] = *reinterpret_cast<const bf16x8*>(
                Bw + (size_t)(col0 + nt * 16 + lr) * CC + k0 + 8 * lg);
#pragma unroll
        for (int mt = 0; mt < 2; ++mt)
#pragma unroll
            for (int nt = 0; nt < 2; ++nt)
                acc[mt][nt] = __builtin_amdgcn_mfma_f32_16x16x32_bf16(
                    af[mt], bfr[nt], acc[mt][nt], 0, 0, 0);
    }
#pragma unroll
    for (int mt = 0; mt < 2; ++mt)
#pragma unroll
        for (int nt = 0; nt < 2; ++nt)
#pragma unroll
            for (int r = 0; r < 4; ++r) {
                int row = row0 + mt * 16 + lg * 4 + r;
                int col = col0 + nt * 16 + lr;
                float bv = bias[col];
                if ((col % 192) < DKK) bv *= QSCALE;
                Cout[(size_t)row * QD + col] = (bf16)(acc[mt][nt][r] + bv);
            }
}

// ---------------------------------------------------------------------------
// V slice of qkv -> vt [B][NH][DK][N] bf16 (so PV A-fragments are contiguous)
__global__ __launch_bounds__(256) void k_transpose_v(const bf16* __restrict__ qkv,
                                                     bf16* __restrict__ vt) {
    int bid = blockIdx.x;                 // B * NH * (N/64) = 2048
    int nt = bid & 15;
    int h  = (bid >> 4) & 3;
    int b  = bid >> 6;
    __shared__ bf16 lds[64][65];
    int t = threadIdx.x;
#pragma unroll
    for (int rep = 0; rep < 16; ++rep) {
        int idx = rep * 256 + t;
        int n = idx >> 6, d = idx & 63;
        lds[n][d] = qkv[(size_t)(b * NN + nt * 64 + n) * QD + h * 192 + 128 + d];
    }
    __syncthreads();
#pragma unroll
    for (int rep = 0; rep < 16; ++rep) {
        int idx = rep * 256 + t;
        int d = idx >> 6, n = idx & 63;
        vt[((size_t)(b * NHH + h) * DKK + d) * NN + nt * 64 + n] = lds[n][d];
    }
}

// ---------------------------------------------------------------------------
// Flash attention, fully-swapped 32x32 MFMA structure (m214-style):
//   S^T[key][q] = mfma(A=K, B=Q)  -> lane holds 16 keys for q = lane&31
//   softmax entirely in-register (permlane32_swap for the cross-half reduce)
//   P -> B-frag via cvt_pk_bf16 + permlane32_swap (T12)
//   O^T[d][q]  = mfma(A=V^T, B=P) -> rescale/normalize factors live in-lane
// 1 wave = 32 q-rows; block = 4 waves = 128 q-rows of one (b,h).
// launch_bounds(256,4): cap VGPR at 128 (grid supplies only 16 waves/CU anyway)
// so the s/p/w working set stays in registers instead of spilling to scratch.
__global__ __launch_bounds__(256, 4) void k_attn(const bf16* __restrict__ qkv,
                                                 const bf16* __restrict__ vt,
                                                 bf16* __restrict__ ctx) {
    int bid = blockIdx.x;                 // B * NH * (N/128) = 1024
    int qt = bid & 7;
    int h  = (bid >> 3) & 3;
    int b  = bid >> 5;
    int wave = threadIdx.x >> 6, lane = threadIdx.x & 63;
    int lq = lane & 31, hi = lane >> 5;
    int q0 = qt * 128 + wave * 32;

    const bf16* qkb = qkv + (size_t)b * NN * QD;
    // Q B-frag: lane holds col q = q0+lq, k-elems d = 16*dk + 8*hi + j
    const bf16* qrow = qkb + (size_t)(q0 + lq) * QD + h * 192 + 8 * hi;
    bf16x8 qf[4];
#pragma unroll
    for (int dk = 0; dk < 4; ++dk)
        qf[dk] = *reinterpret_cast<const bf16x8*>(qrow + 16 * dk);

    // K A-frag base: row key = kb+lq, k-elems d = 16*dk + 8*hi + j
    const bf16* kp = qkb + h * 192 + 64 + (size_t)lq * QD + 8 * hi;
    // V^T A-frag base: row d = 32*t + lq, k-elems key = kb + 16*kk + 8*hi + j
    const bf16* vp = vt + (size_t)(b * NHH + h) * DKK * NN + (size_t)lq * NN + 8 * hi;

    f32x16 acc0 = {}, acc1 = {};          // O^T: rows d (d<32 / d>=32), col q=lq
    float m = -1e30f, l = 0.f;            // per-lane (q = lq); l is half-partial

    // software pipeline: K-fragments for iteration kb preloaded as kf[]
    bf16x8 kf[4];
#pragma unroll
    for (int dk = 0; dk < 4; ++dk)
        kf[dk] = *reinterpret_cast<const bf16x8*>(kp + 16 * dk);

    for (int kb = 0; kb < NN; kb += 32) {
        // issue V loads for THIS iteration early (consumed after softmax)
        const bf16* vpp = vp + kb;
        bf16x8 vf[4];
        vf[0] = *reinterpret_cast<const bf16x8*>(vpp);
        vf[1] = *reinterpret_cast<const bf16x8*>(vpp + 16);
        vf[2] = *reinterpret_cast<const bf16x8*>(vpp + 32 * NN);
        vf[3] = *reinterpret_cast<const bf16x8*>(vpp + 32 * NN + 16);

        f32x16 s = {};
#pragma unroll
        for (int dk = 0; dk < 4; ++dk)
            s = __builtin_amdgcn_mfma_f32_32x32x16_bf16(kf[dk], qf[dk], s, 0, 0, 0);

        // issue K loads for NEXT iteration (wrap to 0 on last: always valid)
        {
            int kb2 = (kb + 32 < NN) ? kb + 32 : 0;
            const bf16* kpp = kp + (size_t)kb2 * QD;
#pragma unroll
            for (int dk = 0; dk < 4; ++dk)
                kf[dk] = *reinterpret_cast<const bf16x8*>(kpp + 16 * dk);
        }

        // s[r] = S^T[key = (r&3)+8*(r>>2)+4*hi + kb][q = lq]   (log2 domain)
        // tree max (depth 4) instead of a 15-deep serial chain
        float t0, t1, t2t, t3;
        t0 = fmaxf(s[0], s[1]);  t1 = fmaxf(s[2], s[3]);
        t2t = fmaxf(s[4], s[5]); t3 = fmaxf(s[6], s[7]);
        t0 = fmaxf(t0, t1);      t2t = fmaxf(t2t, t3);
        float pm0 = fmaxf(t0, t2t);
        t0 = fmaxf(s[8], s[9]);   t1 = fmaxf(s[10], s[11]);
        t2t = fmaxf(s[12], s[13]); t3 = fmaxf(s[14], s[15]);
        t0 = fmaxf(t0, t1);       t2t = fmaxf(t2t, t3);
        float pm = fmaxf(pm0, fmaxf(t0, t2t));
        {   // combine with the other 16 keys (lane ^ 32)
            float a = pm, b2 = pm;
            asm("v_permlane32_swap_b32 %0, %1" : "+v"(a), "+v"(b2));
            pm = fmaxf(a, b2);
        }
        // defer-max (T13): rescale only when max grew by > 8 (P bounded by 256)
        if (__any(pm > m + 8.f)) {
            float nm = fmaxf(m, pm);
            float corr = __builtin_amdgcn_exp2f(m - nm);
            l *= corr;
            acc0 *= corr;
            acc1 *= corr;
            m = nm;
        }
        float p[16];
        float ls = 0.f;
#pragma unroll
        for (int i = 0; i < 16; ++i) {
            p[i] = __builtin_amdgcn_exp2f(s[i] - m);
            ls += p[i];
        }
        l += ls;
        // T12: pack P into the two PV B-frags (keys 0-15, keys 16-31).
        // word j of frag must hold keys {16*kk + 8*hi + 2j, +1}.
        // cvtpk(p0,p1):  hi=0 {k0,k1},  hi=1 {k4,k5}
        // cvtpk(p4,p5):  hi=0 {k8,k9},  hi=1 {k12,k13}
        // permlane32_swap of the pair -> word0 {k0k1|k8k9}, word2 {k4k5|k12k13}
        unsigned w[8];
#pragma unroll
        for (int g = 0; g < 2; ++g) {
#pragma unroll
            for (int j = 0; j < 4; ++j) {
                unsigned t;
                asm("v_cvt_pk_bf16_f32 %0, %1, %2"
                    : "=v"(t) : "v"(p[8 * g + 2 * j]), "v"(p[8 * g + 2 * j + 1]));
                w[4 * g + j] = t;
            }
            asm("v_permlane32_swap_b32 %0, %1" : "+v"(w[4 * g + 0]), "+v"(w[4 * g + 2]));
            asm("v_permlane32_swap_b32 %0, %1" : "+v"(w[4 * g + 1]), "+v"(w[4 * g + 3]));
        }
        union { unsigned u[4]; bf16x8 v; } pu0, pu1;
#pragma unroll
        for (int j = 0; j < 4; ++j) { pu0.u[j] = w[j]; pu1.u[j] = w[4 + j]; }

        acc0 = __builtin_amdgcn_mfma_f32_32x32x16_bf16(vf[0], pu0.v, acc0, 0, 0, 0);
        acc0 = __builtin_amdgcn_mfma_f32_32x32x16_bf16(vf[1], pu1.v, acc0, 0, 0, 0);
        acc1 = __builtin_amdgcn_mfma_f32_32x32x16_bf16(vf[2], pu0.v, acc1, 0, 0, 0);
        acc1 = __builtin_amdgcn_mfma_f32_32x32x16_bf16(vf[3], pu1.v, acc1, 0, 0, 0);
    }

    // combine the two key-half partial sums of l, normalize (all in-lane: q=lq)
    {
        float a = l, b2 = l;
        asm("v_permlane32_swap_b32 %0, %1" : "+v"(a), "+v"(b2));
        l = a + b2;
    }
    float inv = 1.0f / l;

    // O^T -> O transpose via per-wave LDS tile (pitch 68 bf16: 2-way-free writes,
    // 8B-aligned b64 reads), then coalesced 16B global stores.
    __shared__ bf16 tl[4][32][68];
#pragma unroll
    for (int r = 0; r < 16; ++r) {
        int d = (r & 3) + 8 * (r >> 2) + 4 * hi;
        tl[wave][lq][d]      = (bf16)(acc0[r] * inv);
        tl[wave][lq][d + 32] = (bf16)(acc1[r] * inv);
    }
    __syncthreads();
    bf16* cb = ctx + ((size_t)(b * NN + q0)) * 256 + h * 64;
#pragma unroll
    for (int r = 0; r < 4; ++r) {
        int q = 8 * r + (lane >> 3);
        int d0 = (lane & 7) * 8;
        uint2 lo  = *reinterpret_cast<const uint2*>(&tl[wave][q][d0]);
        uint2 hi2 = *reinterpret_cast<const uint2*>(&tl[wave][q][d0 + 4]);
        uint4 o4 = make_uint4(lo.x, lo.y, hi2.x, hi2.y);
        *reinterpret_cast<uint4*>(cb + (size_t)q * 256 + d0) = o4;
    }
}

// ---------------------------------------------------------------------------
// Out GEMM + bias + residual, transposed epilogue to [B][C][N] f32.
__global__ __launch_bounds__(256, 4) void k_gemm_out(const bf16* __restrict__ A,
                                                     const bf16* __restrict__ Bw,
                                                     const float* __restrict__ bias,
                                                     const float* __restrict__ x,
                                                     float* __restrict__ out) {
    int bid = blockIdx.x;                 // (32768/64) * (256/64) = 2048
    int ntile = bid & 3;
    int mtile = bid >> 2;
    int wave = threadIdx.x >> 6, lane = threadIdx.x & 63;
    int wm = wave >> 1, wn = wave & 1;
    int lr = lane & 15, lg = lane >> 4;
    int row0 = mtile * 64 + wm * 32;
    int col0 = ntile * 64 + wn * 32;
    f32x4 acc[2][2] = {};
    for (int k0 = 0; k0 < CC; k0 += 32) {
        bf16x8 af[2], bfr[2];
#pragma unroll
        for (int mt = 0; mt < 2; ++mt)
            af[mt] = *reinterpret_cast<const bf16x8*>(
                A + (size_t)(row0 + mt * 16 + lr) * CC + k0 + 8 * lg);
#pragma unroll
        for (int nt = 0; nt < 2; ++nt)
            bfr[nt] = *reinterpret_cast<const bf16x8*>(
                Bw + (size_t)(col0 + nt * 16 + lr) * CC + k0 + 8 * lg);
#pragma unroll
        for (int mt = 0; mt < 2; ++mt)
#pragma unroll
            for (int nt = 0; nt < 2; ++nt)
                acc[mt][nt] = __builtin_amdgcn_mfma_f32_16x16x32_bf16(
                    af[mt], bfr[nt], acc[mt][nt], 0, 0, 0);
    }
    __shared__ float lds[64][65];
#pragma unroll
    for (int mt = 0; mt < 2; ++mt)
#pragma unroll
        for (int nt = 0; nt < 2; ++nt)
#pragma unroll
            for (int r = 0; r < 4; ++r)
                lds[wm * 32 + mt * 16 + lg * 4 + r][wn * 32 + nt * 16 + lr] =
                    acc[mt][nt][r];
    __syncthreads();
    int b = mtile >> 4;
    int nbase = (mtile & 15) * 64;
#pragma unroll
    for (int rep = 0; rep < 16; ++rep) {
        int idx = rep * 256 + threadIdx.x;
        int nl = idx & 63, cl = idx >> 6;
        int c = ntile * 64 + cl;
        size_t o = ((size_t)b * CC + c) * NN + nbase + nl;
        out[o] = lds[nl][cl] + bias[c] + x[o];   // coalesced read+write over n
    }
}

// ---------------------------------------------------------------------------
extern "C" void kernel_launch(void* const* d_in, const int* in_sizes, int n_in,
                              void* d_out, int out_size, void* d_ws, size_t ws_size,
                              hipStream_t stream) {
    const float* x      = (const float*)d_in[0];
    const float* proj_w = (const float*)d_in[1];
    const float* proj_b = (const float*)d_in[2];
    const float* out_w  = (const float*)d_in[3];
    const float* out_b  = (const float*)d_in[4];
    float* out = (float*)d_out;

    // workspace layout (bf16 elements); ctx aliases xs (xs dead after QKV GEMM)
    bf16* xs  = (bf16*)d_ws;                       // 32768*256
    bf16* qkv = xs + (size_t)32768 * 256;          // 32768*768
    bf16* vt  = qkv + (size_t)32768 * 768;         // 32*4*64*1024
    bf16* pwt = vt + (size_t)8388608;              // 768*256
    bf16* owt = pwt + (size_t)768 * 256;           // 256*256
    bf16* ctx = xs;

    k_prep_w     <<<dim3(768),  dim3(256), 0, stream>>>(proj_w, out_w, pwt, owt);
    k_transpose_x<<<dim3(2048), dim3(256), 0, stream>>>(x, xs);
    k_gemm_qkv   <<<dim3(6144), dim3(256), 0, stream>>>(xs, pwt, proj_b, qkv);
    k_transpose_v<<<dim3(2048), dim3(256), 0, stream>>>(qkv, vt);
    k_attn       <<<dim3(1024), dim3(256), 0, stream>>>(qkv, vt, ctx);
    k_gemm_out   <<<dim3(2048), dim3(256), 0, stream>>>(ctx, owt, out_b, x, out);
}

// Round 4
// 193.891 us; speedup vs baseline: 1.9986x; 1.3855x over previous
//
#include <hip/hip_runtime.h>
#include <hip/hip_bf16.h>

// Problem constants
#define BB  32
#define CC  256
#define NN  1024           // H*W
#define NHH 4
#define DKK 64
#define QD  768            // 3 * NH * DK
// softmax in log2 domain: fold (1/sqrt(64)) * log2(e) into q (weights+bias)
#define QSCALE 0.18033688011112042f

typedef __bf16 bf16;
typedef __bf16 bf16x8 __attribute__((ext_vector_type(8)));
typedef float  f32x4  __attribute__((ext_vector_type(4)));
typedef float  f32x16 __attribute__((ext_vector_type(16)));

typedef __attribute__((address_space(1))) const void g_void;
typedef __attribute__((address_space(3))) void l_void;

// ---------------------------------------------------------------------------
// Convert weights to bf16. pwt keeps proj_w's native [o][c] layout (that is
// exactly the B^T row-major layout the MFMA B-fragment wants); q-rows get the
// softmax scale folded in. owt = out_w native [c][o] layout (B^T for GEMM2).
__global__ __launch_bounds__(256) void k_prep_w(const float* __restrict__ proj_w,
                                                const float* __restrict__ out_w,
                                                bf16* __restrict__ pwt,
                                                bf16* __restrict__ owt) {
    int i = blockIdx.x * 256 + threadIdx.x;   // grid covers 768*256
    if (i < QD * CC) {
        int o = i / CC;
        float v = proj_w[i];
        if ((o % 192) < DKK) v *= QSCALE;     // q rows
        pwt[i] = (bf16)v;
    }
    if (i < CC * CC) {
        owt[i] = (bf16)out_w[i];
    }
}

// ---------------------------------------------------------------------------
// x [B][C][N] f32  ->  xs [B*N][C] bf16   (LDS-tiled transpose, 64x64 tiles)
__global__ __launch_bounds__(256) void k_transpose_x(const float* __restrict__ x,
                                                     bf16* __restrict__ xs) {
    int bid = blockIdx.x;                 // B * (C/64) * (N/64) = 2048
    int nt = bid & 15;
    int ct = (bid >> 4) & 3;
    int b  = bid >> 6;
    __shared__ float lds[64][65];
    int t = threadIdx.x;
    const float* xp = x + ((size_t)b * CC + ct * 64) * NN + nt * 64;
#pragma unroll
    for (int rep = 0; rep < 16; ++rep) {
        int idx = rep * 256 + t;
        int c = idx >> 6, n = idx & 63;
        lds[c][n] = xp[(size_t)c * NN + n];          // coalesced over n
    }
    __syncthreads();
    bf16* xo = xs + ((size_t)b * NN + nt * 64) * CC + ct * 64;
#pragma unroll
    for (int rep = 0; rep < 16; ++rep) {
        int idx = rep * 256 + t;
        int c = idx & 63, n = idx >> 6;
        xo[(size_t)n * CC + c] = (bf16)lds[c][n];    // coalesced over c
    }
}

// ---------------------------------------------------------------------------
// QKV GEMM: qkv[row][col] = xs[row][:] . pwt[col][:] + bias  (M=32768,K=256,N=768)
// 64x64 tile, 4 waves (2x2), wave = 32x32 via 2x2 16x16x32 MFMA fragments.
__global__ __launch_bounds__(256, 4) void k_gemm_qkv(const bf16* __restrict__ A,
                                                     const bf16* __restrict__ Bw,
                                                     const float* __restrict__ bias,
                                                     bf16* __restrict__ Cout) {
    int bid = blockIdx.x;                 // (32768/64) * (768/64) = 6144
    int ntile = bid % 12;
    int mtile = bid / 12;
    int wave = threadIdx.x >> 6, lane = threadIdx.x & 63;
    int wm = wave >> 1, wn = wave & 1;
    int lr = lane & 15, lg = lane >> 4;
    int row0 = mtile * 64 + wm * 32;
    int col0 = ntile * 64 + wn * 32;
    f32x4 acc[2][2] = {};
    for (int k0 = 0; k0 < CC; k0 += 32) {
        bf16x8 af[2], bfr[2];
#pragma unroll
        for (int mt = 0; mt < 2; ++mt)
            af[mt] = *reinterpret_cast<const bf16x8*>(
                A + (size_t)(row0 + mt * 16 + lr) * CC + k0 + 8 * lg);
#pragma unroll
        for (int nt = 0; nt < 2; ++nt)
            bfr[nt] = *reinterpret_cast<const bf16x8*>(
                Bw + (size_t)(col0 + nt * 16 + lr) * CC + k0 + 8 * lg);
#pragma unroll
        for (int mt = 0; mt < 2; ++mt)
#pragma unroll
            for (int nt = 0; nt < 2; ++nt)
                acc[mt][nt] = __builtin_amdgcn_mfma_f32_16x16x32_bf16(
                    af[mt], bfr[nt], acc[mt][nt], 0, 0, 0);
    }
#pragma unroll
    for (int mt = 0; mt < 2; ++mt)
#pragma unroll
        for (int nt = 0; nt < 2; ++nt)
#pragma unroll
            for (int r = 0; r < 4; ++r) {
                int row = row0 + mt * 16 + lg * 4 + r;
                int col = col0 + nt * 16 + lr;
                float bv = bias[col];
                if ((col % 192) < DKK) bv *= QSCALE;
                Cout[(size_t)row * QD + col] = (bf16)(acc[mt][nt][r] + bv);
            }
}

// ---------------------------------------------------------------------------
// V slice of qkv -> vt tile-blocked [b*NH+h][kb][d=0..63][j=0..31] bf16:
// each 32-key V^T tile is a contiguous 4KB block (perfect staging source).
__global__ __launch_bounds__(256) void k_transpose_v(const bf16* __restrict__ qkv,
                                                     bf16* __restrict__ vt) {
    int bid = blockIdx.x;                 // B * NH * (N/64) = 2048
    int nt = bid & 15;
    int h  = (bid >> 4) & 3;
    int b  = bid >> 6;
    __shared__ bf16 lds[64][65];
    int t = threadIdx.x;
#pragma unroll
    for (int rep = 0; rep < 16; ++rep) {
        int idx = rep * 256 + t;
        int n = idx >> 6, d = idx & 63;
        lds[n][d] = qkv[(size_t)(b * NN + nt * 64 + n) * QD + h * 192 + 128 + d];
    }
    __syncthreads();
    size_t tb = ((size_t)(b * NHH + h) * 32 + nt * 2) * 2048;
#pragma unroll
    for (int rep = 0; rep < 16; ++rep) {
        int idx = rep * 256 + t;
        int d = idx >> 6, nl = idx & 63;
        vt[tb + (size_t)(nl >> 5) * 2048 + d * 32 + (nl & 31)] = lds[nl][d];
    }
}

// ---------------------------------------------------------------------------
// Flash attention, fully-swapped 32x32 MFMA structure with cooperative LDS
// staging (T3-minimal 2-phase double-buffer):
//   - K tile (32 keys x 64 d, 4KB) + V^T tile (64 d x 32 keys, 4KB) staged per
//     32-key block via global_load_lds(16B), split across the 4 waves.
//   - Rule #21: linear LDS dest + pre-swizzled global SOURCE + swizzled READ.
//     K swizzle: chunk ^= (row&7) (8 chunks/row); V: chunk ^= ((row>>1)&3).
//   - S^T = mfma(K, Q); in-register softmax; T12 pack; O^T = mfma(V^T, P).
// Block decode puts all 8 q-tiles of one (b,h) on the same XCD (bid%8=bh%8).
__global__ __launch_bounds__(256, 4) void k_attn(const bf16* __restrict__ qkv,
                                                 const bf16* __restrict__ vt,
                                                 bf16* __restrict__ ctx) {
    int bid = blockIdx.x;                 // qt(8) x bh(128) = 1024
    int qt = bid >> 7;
    int bh = bid & 127;
    int b  = bh >> 2;
    int h  = bh & 3;
    int wave = threadIdx.x >> 6, lane = threadIdx.x & 63;
    int lq = lane & 31, hi = lane >> 5;
    int q0 = qt * 128 + wave * 32;

    __shared__ __align__(16) bf16 Kbuf[2][2048];  // 2 x [32 rows][64 d] (4KB)
    __shared__ __align__(16) bf16 Vbuf[2][2048];  // 2 x [64 rows][32 j] (4KB)
    __shared__ bf16 tl[4][32][68];

    const bf16* qkb = qkv + (size_t)b * NN * QD;
    // Q B-frag: lane holds col q = q0+lq, k-elems d = 16*dk + 8*hi + j
    const bf16* qrow = qkb + (size_t)(q0 + lq) * QD + h * 192 + 8 * hi;
    bf16x8 qf[4];
#pragma unroll
    for (int dk = 0; dk < 4; ++dk)
        qf[dk] = *reinterpret_cast<const bf16x8*>(qrow + 16 * dk);

    const bf16* kglob = qkb + h * 192 + 64;              // K slice of qkv
    const bf16* vtile = vt + (size_t)bh * 32 * 2048;     // V^T tiles of (b,h)

    // staging: wave w covers quarter w of the K tile and of the V tile
    int krow = wave * 8 + (lane >> 3), kc = lane & 7;    // K: 8 rows x 8 chunks
    const bf16* ksrc0 = kglob + (size_t)krow * QD + ((kc ^ (krow & 7)) * 8);
    int vrow = wave * 16 + (lane >> 2), vc = lane & 3;   // V: 16 rows x 4 chunks
    const bf16* vsrc0 = vtile + (size_t)vrow * 32 + ((vc ^ ((vrow >> 1) & 3)) * 8);

#define STAGE(kb, sel)                                                          \
    do {                                                                        \
        __builtin_amdgcn_global_load_lds(                                       \
            (g_void*)(ksrc0 + (size_t)(kb) * 32 * QD),                          \
            (l_void*)&Kbuf[sel][wave * 512], 16, 0, 0);                         \
        __builtin_amdgcn_global_load_lds(                                       \
            (g_void*)(vsrc0 + (size_t)(kb) * 2048),                             \
            (l_void*)&Vbuf[sel][wave * 512], 16, 0, 0);                         \
    } while (0)

    f32x16 acc0 = {}, acc1 = {};          // O^T: rows d (d<32 / d>=32), col q=lq
    float m = -1e30f, l = 0.f;            // per-lane (q = lq); l is half-partial

    STAGE(0, 0);
    asm volatile("s_waitcnt vmcnt(0)" ::: "memory");
    __builtin_amdgcn_s_barrier();

    int cur = 0;
    for (int t = 0; t < 32; ++t) {
        if (t + 1 < 32) STAGE(t + 1, cur ^ 1);

        // K fragments from LDS (swizzled read)
        f32x16 s = {};
#pragma unroll
        for (int dk = 0; dk < 4; ++dk) {
            bf16x8 kf = *reinterpret_cast<const bf16x8*>(
                &Kbuf[cur][lq * 64 + (((dk * 2 + hi) ^ (lq & 7)) * 8)]);
            s = __builtin_amdgcn_mfma_f32_32x32x16_bf16(kf, qf[dk], s, 0, 0, 0);
        }
        // V fragments issued early so ds_read latency hides under softmax
        bf16x8 vf[4];
        int sw = (lq >> 1) & 3;
        vf[0] = *reinterpret_cast<const bf16x8*>(
            &Vbuf[cur][lq * 32 + ((hi ^ sw) * 8)]);
        vf[1] = *reinterpret_cast<const bf16x8*>(
            &Vbuf[cur][lq * 32 + (((2 + hi) ^ sw) * 8)]);
        vf[2] = *reinterpret_cast<const bf16x8*>(
            &Vbuf[cur][(32 + lq) * 32 + ((hi ^ sw) * 8)]);
        vf[3] = *reinterpret_cast<const bf16x8*>(
            &Vbuf[cur][(32 + lq) * 32 + (((2 + hi) ^ sw) * 8)]);

        // s[r] = S^T[key = (r&3)+8*(r>>2)+4*hi + 32t][q = lq]   (log2 domain)
        float t0, t1, t2t, t3;
        t0 = fmaxf(s[0], s[1]);  t1 = fmaxf(s[2], s[3]);
        t2t = fmaxf(s[4], s[5]); t3 = fmaxf(s[6], s[7]);
        t0 = fmaxf(t0, t1);      t2t = fmaxf(t2t, t3);
        float pm0 = fmaxf(t0, t2t);
        t0 = fmaxf(s[8], s[9]);   t1 = fmaxf(s[10], s[11]);
        t2t = fmaxf(s[12], s[13]); t3 = fmaxf(s[14], s[15]);
        t0 = fmaxf(t0, t1);       t2t = fmaxf(t2t, t3);
        float pm = fmaxf(pm0, fmaxf(t0, t2t));
        {   // combine with the other 16 keys (lane ^ 32)
            float a = pm, b2 = pm;
            asm("v_permlane32_swap_b32 %0, %1" : "+v"(a), "+v"(b2));
            pm = fmaxf(a, b2);
        }
        // defer-max (T13): rescale only when max grew by > 8 (P bounded by 256)
        if (__any(pm > m + 8.f)) {
            float nm = fmaxf(m, pm);
            float corr = __builtin_amdgcn_exp2f(m - nm);
            l *= corr;
            acc0 *= corr;
            acc1 *= corr;
            m = nm;
        }
        float ls = 0.f;
#pragma unroll
        for (int i = 0; i < 16; ++i) {
            s[i] = __builtin_amdgcn_exp2f(s[i] - m);   // reuse s as P (reg save)
            ls += s[i];
        }
        l += ls;
        // T12: pack P into the two PV B-frags (keys 0-15, keys 16-31).
        // word j of frag must hold keys {16*kk + 8*hi + 2j, +1}.
        unsigned w[8];
#pragma unroll
        for (int g = 0; g < 2; ++g) {
#pragma unroll
            for (int j = 0; j < 4; ++j) {
                unsigned tw;
                asm("v_cvt_pk_bf16_f32 %0, %1, %2"
                    : "=v"(tw) : "v"(s[8 * g + 2 * j]), "v"(s[8 * g + 2 * j + 1]));
                w[4 * g + j] = tw;
            }
            asm("v_permlane32_swap_b32 %0, %1" : "+v"(w[4 * g + 0]), "+v"(w[4 * g + 2]));
            asm("v_permlane32_swap_b32 %0, %1" : "+v"(w[4 * g + 1]), "+v"(w[4 * g + 3]));
        }
        union { unsigned u[4]; bf16x8 v; } pu0, pu1;
#pragma unroll
        for (int j = 0; j < 4; ++j) { pu0.u[j] = w[j]; pu1.u[j] = w[4 + j]; }

        acc0 = __builtin_amdgcn_mfma_f32_32x32x16_bf16(vf[0], pu0.v, acc0, 0, 0, 0);
        acc0 = __builtin_amdgcn_mfma_f32_32x32x16_bf16(vf[1], pu1.v, acc0, 0, 0, 0);
        acc1 = __builtin_amdgcn_mfma_f32_32x32x16_bf16(vf[2], pu0.v, acc1, 0, 0, 0);
        acc1 = __builtin_amdgcn_mfma_f32_32x32x16_bf16(vf[3], pu1.v, acc1, 0, 0, 0);

        asm volatile("s_waitcnt vmcnt(0)" ::: "memory");
        __builtin_amdgcn_s_barrier();
        cur ^= 1;
    }
#undef STAGE

    // combine the two key-half partial sums of l, normalize (all in-lane: q=lq)
    {
        float a = l, b2 = l;
        asm("v_permlane32_swap_b32 %0, %1" : "+v"(a), "+v"(b2));
        l = a + b2;
    }
    float inv = 1.0f / l;

    // O^T -> O transpose via per-wave LDS tile (pitch 68 bf16), then coalesced
    // 16B global stores.
#pragma unroll
    for (int r = 0; r < 16; ++r) {
        int d = (r & 3) + 8 * (r >> 2) + 4 * hi;
        tl[wave][lq][d]      = (bf16)(acc0[r] * inv);
        tl[wave][lq][d + 32] = (bf16)(acc1[r] * inv);
    }
    __syncthreads();
    bf16* cb = ctx + ((size_t)(b * NN + q0)) * 256 + h * 64;
#pragma unroll
    for (int r = 0; r < 4; ++r) {
        int q = 8 * r + (lane >> 3);
        int d0 = (lane & 7) * 8;
        uint2 lo  = *reinterpret_cast<const uint2*>(&tl[wave][q][d0]);
        uint2 hi2 = *reinterpret_cast<const uint2*>(&tl[wave][q][d0 + 4]);
        uint4 o4 = make_uint4(lo.x, lo.y, hi2.x, hi2.y);
        *reinterpret_cast<uint4*>(cb + (size_t)q * 256 + d0) = o4;
    }
}

// ---------------------------------------------------------------------------
// Out GEMM + bias + residual, transposed epilogue to [B][C][N] f32.
__global__ __launch_bounds__(256, 4) void k_gemm_out(const bf16* __restrict__ A,
                                                     const bf16* __restrict__ Bw,
                                                     const float* __restrict__ bias,
                                                     const float* __restrict__ x,
                                                     float* __restrict__ out) {
    int bid = blockIdx.x;                 // (32768/64) * (256/64) = 2048
    int ntile = bid & 3;
    int mtile = bid >> 2;
    int wave = threadIdx.x >> 6, lane = threadIdx.x & 63;
    int wm = wave >> 1, wn = wave & 1;
    int lr = lane & 15, lg = lane >> 4;
    int row0 = mtile * 64 + wm * 32;
    int col0 = ntile * 64 + wn * 32;
    f32x4 acc[2][2] = {};
    for (int k0 = 0; k0 < CC; k0 += 32) {
        bf16x8 af[2], bfr[2];
#pragma unroll
        for (int mt = 0; mt < 2; ++mt)
            af[mt] = *reinterpret_cast<const bf16x8*>(
                A + (size_t)(row0 + mt * 16 + lr) * CC + k0 + 8 * lg);
#pragma unroll
        for (int nt = 0; nt < 2; ++nt)
            bfr[nt] = *reinterpret_cast<const bf16x8*>(
                Bw + (size_t)(col0 + nt * 16 + lr) * CC + k0 + 8 * lg);
#pragma unroll
        for (int mt = 0; mt < 2; ++mt)
#pragma unroll
            for (int nt = 0; nt < 2; ++nt)
                acc[mt][nt] = __builtin_amdgcn_mfma_f32_16x16x32_bf16(
                    af[mt], bfr[nt], acc[mt][nt], 0, 0, 0);
    }
    __shared__ float lds[64][65];
#pragma unroll
    for (int mt = 0; mt < 2; ++mt)
#pragma unroll
        for (int nt = 0; nt < 2; ++nt)
#pragma unroll
            for (int r = 0; r < 4; ++r)
                lds[wm * 32 + mt * 16 + lg * 4 + r][wn * 32 + nt * 16 + lr] =
                    acc[mt][nt][r];
    __syncthreads();
    int b = mtile >> 4;
    int nbase = (mtile & 15) * 64;
#pragma unroll
    for (int rep = 0; rep < 16; ++rep) {
        int idx = rep * 256 + threadIdx.x;
        int nl = idx & 63, cl = idx >> 6;
        int c = ntile * 64 + cl;
        size_t o = ((size_t)b * CC + c) * NN + nbase + nl;
        out[o] = lds[nl][cl] + bias[c] + x[o];   // coalesced read+write over n
    }
}

// ---------------------------------------------------------------------------
extern "C" void kernel_launch(void* const* d_in, const int* in_sizes, int n_in,
                              void* d_out, int out_size, void* d_ws, size_t ws_size,
                              hipStream_t stream) {
    const float* x      = (const float*)d_in[0];
    const float* proj_w = (const float*)d_in[1];
    const float* proj_b = (const float*)d_in[2];
    const float* out_w  = (const float*)d_in[3];
    const float* out_b  = (const float*)d_in[4];
    float* out = (float*)d_out;

    // workspace layout (bf16 elements); ctx aliases xs (xs dead after QKV GEMM)
    bf16* xs  = (bf16*)d_ws;                       // 32768*256
    bf16* qkv = xs + (size_t)32768 * 256;          // 32768*768
    bf16* vt  = qkv + (size_t)32768 * 768;         // 32*4*64*1024
    bf16* pwt = vt + (size_t)8388608;              // 768*256
    bf16* owt = pwt + (size_t)768 * 256;           // 256*256
    bf16* ctx = xs;

    k_prep_w     <<<dim3(768),  dim3(256), 0, stream>>>(proj_w, out_w, pwt, owt);
    k_transpose_x<<<dim3(2048), dim3(256), 0, stream>>>(x, xs);
    k_gemm_qkv   <<<dim3(6144), dim3(256), 0, stream>>>(xs, pwt, proj_b, qkv);
    k_transpose_v<<<dim3(2048), dim3(256), 0, stream>>>(qkv, vt);
    k_attn       <<<dim3(1024), dim3(256), 0, stream>>>(qkv, vt, ctx);
    k_gemm_out   <<<dim3(2048), dim3(256), 0, stream>>>(ctx, owt, out_b, x, out);
}

// Round 5
// 108.538 us; speedup vs baseline: 3.5703x; 1.7864x over previous
//
#include <hip/hip_runtime.h>
#include <hip/hip_bf16.h>

// Problem constants
#define BB  32
#define CC  256
#define NN  1024           // H*W
#define NHH 4
#define DKK 64
#define QD  768            // 3 * NH * DK
// softmax in log2 domain: fold (1/sqrt(64)) * log2(e) into q (weights+bias)
#define QSCALE 0.18033688011112042f

typedef __bf16 bf16;
typedef __bf16 bf16x8 __attribute__((ext_vector_type(8)));
typedef float  f32x4  __attribute__((ext_vector_type(4)));
typedef float  f32x16 __attribute__((ext_vector_type(16)));

typedef __attribute__((address_space(1))) const void g_void;
typedef __attribute__((address_space(3))) void l_void;

// ---------------------------------------------------------------------------
// Convert weights to bf16. pwt keeps proj_w's native [o][c] layout (that is
// exactly the B^T row-major layout the MFMA B-fragment wants); q-rows get the
// softmax scale folded in. owt = out_w native [c][o] layout (B^T for GEMM2).
__global__ __launch_bounds__(256) void k_prep_w(const float* __restrict__ proj_w,
                                                const float* __restrict__ out_w,
                                                bf16* __restrict__ pwt,
                                                bf16* __restrict__ owt) {
    int i = blockIdx.x * 256 + threadIdx.x;   // grid covers 768*256
    if (i < QD * CC) {
        int o = i / CC;
        float v = proj_w[i];
        if ((o % 192) < DKK) v *= QSCALE;     // q rows
        pwt[i] = (bf16)v;
    }
    if (i < CC * CC) {
        owt[i] = (bf16)out_w[i];
    }
}

// ---------------------------------------------------------------------------
// x [B][C][N] f32  ->  xs [B*N][C] bf16   (LDS-tiled transpose, 64x64 tiles)
__global__ __launch_bounds__(256) void k_transpose_x(const float* __restrict__ x,
                                                     bf16* __restrict__ xs) {
    int bid = blockIdx.x;                 // B * (C/64) * (N/64) = 2048
    int nt = bid & 15;
    int ct = (bid >> 4) & 3;
    int b  = bid >> 6;
    __shared__ float lds[64][65];
    int t = threadIdx.x;
    const float* xp = x + ((size_t)b * CC + ct * 64) * NN + nt * 64;
#pragma unroll
    for (int rep = 0; rep < 16; ++rep) {
        int idx = rep * 256 + t;
        int c = idx >> 6, n = idx & 63;
        lds[c][n] = xp[(size_t)c * NN + n];          // coalesced over n
    }
    __syncthreads();
    bf16* xo = xs + ((size_t)b * NN + nt * 64) * CC + ct * 64;
#pragma unroll
    for (int rep = 0; rep < 16; ++rep) {
        int idx = rep * 256 + t;
        int c = idx & 63, n = idx >> 6;
        xo[(size_t)n * CC + c] = (bf16)lds[c][n];    // coalesced over c
    }
}

// ---------------------------------------------------------------------------
// QKV GEMM, staged: qkv[row][col] = xs[row][:] . pwt[col][:] + bias
// (M=32768, K=256, N=768). 128x128 tile, BK=32, 2-phase double-buffered
// global_load_lds staging. 4 waves (2x2), each 64x64 = 4x4 16x16x32 frags.
// V-section columns are written directly into the tiled vt layout
// ([bh][kb][d][j], 4KB tiles) -> k_transpose_v is fused away.
// LDS swizzle: stored chunk c holds global chunk c ^ ((row>>1)&3); the
// ds_read undoes it -> consecutive-8-lane bank access is uniform.
__global__ __launch_bounds__(256, 4) void k_gemm_qkv(const bf16* __restrict__ A,
                                                     const bf16* __restrict__ Bw,
                                                     const float* __restrict__ bias,
                                                     bf16* __restrict__ qkv,
                                                     bf16* __restrict__ vt) {
    // XCD-bijective swizzle: nwg=1536=8*192; all 6 ntiles x 32 mtiles per XCD
    int l = (blockIdx.x & 7) * 192 + (blockIdx.x >> 3);
    int mtile = l / 6, ntile = l % 6;
    int wave = threadIdx.x >> 6, lane = threadIdx.x & 63;
    int wm = wave >> 1, wn = wave & 1;
    int lr = lane & 15, lg = lane >> 4;
    int row0 = mtile * 128, col0 = ntile * 128;

    __shared__ __align__(16) bf16 Abuf[2][4096];   // [128 rows][32 k] 8KB each
    __shared__ __align__(16) bf16 Bbuf[2][4096];

    // staging sources: instr j covers rows 16j..16j+15; wave does j=w, w+4
    int srow = lane >> 2, sc = lane & 3;
    int rA0 = wave * 16 + srow, rA1 = (wave + 4) * 16 + srow;
    const bf16* a0 = A + (size_t)(row0 + rA0) * CC + ((sc ^ ((rA0 >> 1) & 3)) * 8);
    const bf16* a1 = A + (size_t)(row0 + rA1) * CC + ((sc ^ ((rA1 >> 1) & 3)) * 8);
    const bf16* b0 = Bw + (size_t)(col0 + rA0) * CC + ((sc ^ ((rA0 >> 1) & 3)) * 8);
    const bf16* b1 = Bw + (size_t)(col0 + rA1) * CC + ((sc ^ ((rA1 >> 1) & 3)) * 8);

#define STAGE(ks, sel)                                                          \
    do {                                                                        \
        __builtin_amdgcn_global_load_lds((g_void*)(a0 + (ks) * 32),             \
            (l_void*)&Abuf[sel][wave * 512], 16, 0, 0);                         \
        __builtin_amdgcn_global_load_lds((g_void*)(a1 + (ks) * 32),             \
            (l_void*)&Abuf[sel][(wave + 4) * 512], 16, 0, 0);                   \
        __builtin_amdgcn_global_load_lds((g_void*)(b0 + (ks) * 32),             \
            (l_void*)&Bbuf[sel][wave * 512], 16, 0, 0);                         \
        __builtin_amdgcn_global_load_lds((g_void*)(b1 + (ks) * 32),             \
            (l_void*)&Bbuf[sel][(wave + 4) * 512], 16, 0, 0);                   \
    } while (0)

    f32x4 acc[4][4] = {};
    STAGE(0, 0);
    asm volatile("s_waitcnt vmcnt(0)" ::: "memory");
    __builtin_amdgcn_s_barrier();

    int cur = 0;
    for (int ks = 0; ks < 8; ++ks) {
        if (ks + 1 < 8) STAGE(ks + 1, cur ^ 1);
        bf16x8 af[4], bfm[4];
#pragma unroll
        for (int mt = 0; mt < 4; ++mt) {
            int row = wm * 64 + mt * 16 + lr;
            af[mt] = *reinterpret_cast<const bf16x8*>(
                &Abuf[cur][row * 32 + ((lg ^ ((row >> 1) & 3)) * 8)]);
        }
#pragma unroll
        for (int nt = 0; nt < 4; ++nt) {
            int row = wn * 64 + nt * 16 + lr;
            bfm[nt] = *reinterpret_cast<const bf16x8*>(
                &Bbuf[cur][row * 32 + ((lg ^ ((row >> 1) & 3)) * 8)]);
        }
#pragma unroll
        for (int mt = 0; mt < 4; ++mt)
#pragma unroll
            for (int nt = 0; nt < 4; ++nt)
                acc[mt][nt] = __builtin_amdgcn_mfma_f32_16x16x32_bf16(
                    af[mt], bfm[nt], acc[mt][nt], 0, 0, 0);
        asm volatile("s_waitcnt vmcnt(0)" ::: "memory");
        __builtin_amdgcn_s_barrier();
        cur ^= 1;
    }
#undef STAGE

    // Epilogue: Q/K columns -> qkv (scalar bf16); V columns -> tiled vt.
#pragma unroll
    for (int nt = 0; nt < 4; ++nt) {
        int col = col0 + wn * 64 + nt * 16 + lr;
        int sect = col % 192;                      // frag-uniform section type
        int h = col / 192;
        float bv = bias[col];
        if (sect < DKK) bv *= QSCALE;
#pragma unroll
        for (int mt = 0; mt < 4; ++mt) {
            int rowb = row0 + wm * 64 + mt * 16 + lg * 4;
            if (sect < 128) {                      // Q or K -> qkv layout
#pragma unroll
                for (int rr = 0; rr < 4; ++rr)
                    qkv[(size_t)(rowb + rr) * QD + col] =
                        (bf16)(acc[mt][nt][rr] + bv);
            } else {                               // V -> vt tiled layout
                int d = sect - 128;
                int b = rowb >> 10, n = rowb & 1023;
                int kb = n >> 5, j = n & 31;
                unsigned u0, u1;
                asm("v_cvt_pk_bf16_f32 %0, %1, %2" : "=v"(u0)
                    : "v"(acc[mt][nt][0] + bv), "v"(acc[mt][nt][1] + bv));
                asm("v_cvt_pk_bf16_f32 %0, %1, %2" : "=v"(u1)
                    : "v"(acc[mt][nt][2] + bv), "v"(acc[mt][nt][3] + bv));
                *reinterpret_cast<uint2*>(
                    &vt[(((size_t)(b * NHH + h) * 32 + kb) * 64 + d) * 32 + j]) =
                    make_uint2(u0, u1);
            }
        }
    }
}

// ---------------------------------------------------------------------------
// Flash attention, fully-swapped 32x32 MFMA structure with cooperative LDS
// staging (2-phase double-buffer); see round-4 notes. Unchanged.
__global__ __launch_bounds__(256, 4) void k_attn(const bf16* __restrict__ qkv,
                                                 const bf16* __restrict__ vt,
                                                 bf16* __restrict__ ctx) {
    int bid = blockIdx.x;                 // qt(8) x bh(128) = 1024
    int qt = bid >> 7;
    int bh = bid & 127;
    int b  = bh >> 2;
    int h  = bh & 3;
    int wave = threadIdx.x >> 6, lane = threadIdx.x & 63;
    int lq = lane & 31, hi = lane >> 5;
    int q0 = qt * 128 + wave * 32;

    __shared__ __align__(16) bf16 Kbuf[2][2048];  // 2 x [32 rows][64 d] (4KB)
    __shared__ __align__(16) bf16 Vbuf[2][2048];  // 2 x [64 rows][32 j] (4KB)
    __shared__ bf16 tl[4][32][68];

    const bf16* qkb = qkv + (size_t)b * NN * QD;
    const bf16* qrow = qkb + (size_t)(q0 + lq) * QD + h * 192 + 8 * hi;
    bf16x8 qf[4];
#pragma unroll
    for (int dk = 0; dk < 4; ++dk)
        qf[dk] = *reinterpret_cast<const bf16x8*>(qrow + 16 * dk);

    const bf16* kglob = qkb + h * 192 + 64;              // K slice of qkv
    const bf16* vtile = vt + (size_t)bh * 32 * 2048;     // V^T tiles of (b,h)

    int krow = wave * 8 + (lane >> 3), kc = lane & 7;    // K: 8 rows x 8 chunks
    const bf16* ksrc0 = kglob + (size_t)krow * QD + ((kc ^ (krow & 7)) * 8);
    int vrow = wave * 16 + (lane >> 2), vc = lane & 3;   // V: 16 rows x 4 chunks
    const bf16* vsrc0 = vtile + (size_t)vrow * 32 + ((vc ^ ((vrow >> 1) & 3)) * 8);

#define STAGE(kb, sel)                                                          \
    do {                                                                        \
        __builtin_amdgcn_global_load_lds(                                       \
            (g_void*)(ksrc0 + (size_t)(kb) * 32 * QD),                          \
            (l_void*)&Kbuf[sel][wave * 512], 16, 0, 0);                         \
        __builtin_amdgcn_global_load_lds(                                       \
            (g_void*)(vsrc0 + (size_t)(kb) * 2048),                             \
            (l_void*)&Vbuf[sel][wave * 512], 16, 0, 0);                         \
    } while (0)

    f32x16 acc0 = {}, acc1 = {};          // O^T: rows d (d<32 / d>=32), col q=lq
    float m = -1e30f, l = 0.f;            // per-lane (q = lq); l is half-partial

    STAGE(0, 0);
    asm volatile("s_waitcnt vmcnt(0)" ::: "memory");
    __builtin_amdgcn_s_barrier();

    int cur = 0;
    for (int t = 0; t < 32; ++t) {
        if (t + 1 < 32) STAGE(t + 1, cur ^ 1);

        f32x16 s = {};
#pragma unroll
        for (int dk = 0; dk < 4; ++dk) {
            bf16x8 kf = *reinterpret_cast<const bf16x8*>(
                &Kbuf[cur][lq * 64 + (((dk * 2 + hi) ^ (lq & 7)) * 8)]);
            s = __builtin_amdgcn_mfma_f32_32x32x16_bf16(kf, qf[dk], s, 0, 0, 0);
        }
        bf16x8 vf[4];
        int sw = (lq >> 1) & 3;
        vf[0] = *reinterpret_cast<const bf16x8*>(
            &Vbuf[cur][lq * 32 + ((hi ^ sw) * 8)]);
        vf[1] = *reinterpret_cast<const bf16x8*>(
            &Vbuf[cur][lq * 32 + (((2 + hi) ^ sw) * 8)]);
        vf[2] = *reinterpret_cast<const bf16x8*>(
            &Vbuf[cur][(32 + lq) * 32 + ((hi ^ sw) * 8)]);
        vf[3] = *reinterpret_cast<const bf16x8*>(
            &Vbuf[cur][(32 + lq) * 32 + (((2 + hi) ^ sw) * 8)]);

        float t0, t1, t2t, t3;
        t0 = fmaxf(s[0], s[1]);  t1 = fmaxf(s[2], s[3]);
        t2t = fmaxf(s[4], s[5]); t3 = fmaxf(s[6], s[7]);
        t0 = fmaxf(t0, t1);      t2t = fmaxf(t2t, t3);
        float pm0 = fmaxf(t0, t2t);
        t0 = fmaxf(s[8], s[9]);   t1 = fmaxf(s[10], s[11]);
        t2t = fmaxf(s[12], s[13]); t3 = fmaxf(s[14], s[15]);
        t0 = fmaxf(t0, t1);       t2t = fmaxf(t2t, t3);
        float pm = fmaxf(pm0, fmaxf(t0, t2t));
        {
            float a = pm, b2 = pm;
            asm("v_permlane32_swap_b32 %0, %1" : "+v"(a), "+v"(b2));
            pm = fmaxf(a, b2);
        }
        if (__any(pm > m + 8.f)) {
            float nm = fmaxf(m, pm);
            float corr = __builtin_amdgcn_exp2f(m - nm);
            l *= corr;
            acc0 *= corr;
            acc1 *= corr;
            m = nm;
        }
        float ls = 0.f;
#pragma unroll
        for (int i = 0; i < 16; ++i) {
            s[i] = __builtin_amdgcn_exp2f(s[i] - m);
            ls += s[i];
        }
        l += ls;
        unsigned w[8];
#pragma unroll
        for (int g = 0; g < 2; ++g) {
#pragma unroll
            for (int j = 0; j < 4; ++j) {
                unsigned tw;
                asm("v_cvt_pk_bf16_f32 %0, %1, %2"
                    : "=v"(tw) : "v"(s[8 * g + 2 * j]), "v"(s[8 * g + 2 * j + 1]));
                w[4 * g + j] = tw;
            }
            asm("v_permlane32_swap_b32 %0, %1" : "+v"(w[4 * g + 0]), "+v"(w[4 * g + 2]));
            asm("v_permlane32_swap_b32 %0, %1" : "+v"(w[4 * g + 1]), "+v"(w[4 * g + 3]));
        }
        union { unsigned u[4]; bf16x8 v; } pu0, pu1;
#pragma unroll
        for (int j = 0; j < 4; ++j) { pu0.u[j] = w[j]; pu1.u[j] = w[4 + j]; }

        acc0 = __builtin_amdgcn_mfma_f32_32x32x16_bf16(vf[0], pu0.v, acc0, 0, 0, 0);
        acc0 = __builtin_amdgcn_mfma_f32_32x32x16_bf16(vf[1], pu1.v, acc0, 0, 0, 0);
        acc1 = __builtin_amdgcn_mfma_f32_32x32x16_bf16(vf[2], pu0.v, acc1, 0, 0, 0);
        acc1 = __builtin_amdgcn_mfma_f32_32x32x16_bf16(vf[3], pu1.v, acc1, 0, 0, 0);

        asm volatile("s_waitcnt vmcnt(0)" ::: "memory");
        __builtin_amdgcn_s_barrier();
        cur ^= 1;
    }
#undef STAGE

    {
        float a = l, b2 = l;
        asm("v_permlane32_swap_b32 %0, %1" : "+v"(a), "+v"(b2));
        l = a + b2;
    }
    float inv = 1.0f / l;

#pragma unroll
    for (int r = 0; r < 16; ++r) {
        int d = (r & 3) + 8 * (r >> 2) + 4 * hi;
        tl[wave][lq][d]      = (bf16)(acc0[r] * inv);
        tl[wave][lq][d + 32] = (bf16)(acc1[r] * inv);
    }
    __syncthreads();
    bf16* cb = ctx + ((size_t)(b * NN + q0)) * 256 + h * 64;
#pragma unroll
    for (int r = 0; r < 4; ++r) {
        int q = 8 * r + (lane >> 3);
        int d0 = (lane & 7) * 8;
        uint2 lo  = *reinterpret_cast<const uint2*>(&tl[wave][q][d0]);
        uint2 hi2 = *reinterpret_cast<const uint2*>(&tl[wave][q][d0 + 4]);
        uint4 o4 = make_uint4(lo.x, lo.y, hi2.x, hi2.y);
        *reinterpret_cast<uint4*>(cb + (size_t)q * 256 + d0) = o4;
    }
}

// ---------------------------------------------------------------------------
// Out GEMM + bias + residual, staged like k_gemm_qkv (128x64 tile, BK=32),
// register-direct transposed epilogue: D-frag rows are n-contiguous per lane,
// so each lane stores float4 along n straight to out[b][c][n] (+ bias + x).
__global__ __launch_bounds__(256, 4) void k_gemm_out(const bf16* __restrict__ A,
                                                     const bf16* __restrict__ Bw,
                                                     const float* __restrict__ bias,
                                                     const float* __restrict__ x,
                                                     float* __restrict__ out) {
    // nwg = 256*4 = 1024 = 8*128
    int l = (blockIdx.x & 7) * 128 + (blockIdx.x >> 3);
    int mtile = l >> 2, ntile = l & 3;
    int wave = threadIdx.x >> 6, lane = threadIdx.x & 63;
    int wm = wave >> 1, wn = wave & 1;
    int lr = lane & 15, lg = lane >> 4;
    int row0 = mtile * 128, col0 = ntile * 64;

    __shared__ __align__(16) bf16 Abuf[2][4096];   // [128][32]
    __shared__ __align__(16) bf16 Bbuf[2][2048];   // [64][32]

    int srow = lane >> 2, sc = lane & 3;
    int rA0 = wave * 16 + srow, rA1 = (wave + 4) * 16 + srow;
    const bf16* a0 = A + (size_t)(row0 + rA0) * CC + ((sc ^ ((rA0 >> 1) & 3)) * 8);
    const bf16* a1 = A + (size_t)(row0 + rA1) * CC + ((sc ^ ((rA1 >> 1) & 3)) * 8);
    const bf16* b0 = Bw + (size_t)(col0 + rA0) * CC + ((sc ^ ((rA0 >> 1) & 3)) * 8);

#define STAGE(ks, sel)                                                          \
    do {                                                                        \
        __builtin_amdgcn_global_load_lds((g_void*)(a0 + (ks) * 32),             \
            (l_void*)&Abuf[sel][wave * 512], 16, 0, 0);                         \
        __builtin_amdgcn_global_load_lds((g_void*)(a1 + (ks) * 32),             \
            (l_void*)&Abuf[sel][(wave + 4) * 512], 16, 0, 0);                   \
        __builtin_amdgcn_global_load_lds((g_void*)(b0 + (ks) * 32),             \
            (l_void*)&Bbuf[sel][wave * 512], 16, 0, 0);                         \
    } while (0)

    f32x4 acc[4][2] = {};
    STAGE(0, 0);
    asm volatile("s_waitcnt vmcnt(0)" ::: "memory");
    __builtin_amdgcn_s_barrier();

    int cur = 0;
    for (int ks = 0; ks < 8; ++ks) {
        if (ks + 1 < 8) STAGE(ks + 1, cur ^ 1);
        bf16x8 af[4], bfm[2];
#pragma unroll
        for (int mt = 0; mt < 4; ++mt) {
            int row = wm * 64 + mt * 16 + lr;
            af[mt] = *reinterpret_cast<const bf16x8*>(
                &Abuf[cur][row * 32 + ((lg ^ ((row >> 1) & 3)) * 8)]);
        }
#pragma unroll
        for (int nt = 0; nt < 2; ++nt) {
            int row = wn * 32 + nt * 16 + lr;
            bfm[nt] = *reinterpret_cast<const bf16x8*>(
                &Bbuf[cur][row * 32 + ((lg ^ ((row >> 1) & 3)) * 8)]);
        }
#pragma unroll
        for (int mt = 0; mt < 4; ++mt)
#pragma unroll
            for (int nt = 0; nt < 2; ++nt)
                acc[mt][nt] = __builtin_amdgcn_mfma_f32_16x16x32_bf16(
                    af[mt], bfm[nt], acc[mt][nt], 0, 0, 0);
        asm volatile("s_waitcnt vmcnt(0)" ::: "memory");
        __builtin_amdgcn_s_barrier();
        cur ^= 1;
    }
#undef STAGE

#pragma unroll
    for (int nt = 0; nt < 2; ++nt) {
        int c = col0 + wn * 32 + nt * 16 + lr;
        float bv = bias[c];
#pragma unroll
        for (int mt = 0; mt < 4; ++mt) {
            int rowb = row0 + wm * 64 + mt * 16 + lg * 4;
            int b = rowb >> 10, n = rowb & 1023;
            size_t o = ((size_t)b * CC + c) * NN + n;
            f32x4 xr = *reinterpret_cast<const f32x4*>(&x[o]);
            f32x4 r = acc[mt][nt] + bv + xr;
            *reinterpret_cast<f32x4*>(&out[o]) = r;
        }
    }
}

// ---------------------------------------------------------------------------
extern "C" void kernel_launch(void* const* d_in, const int* in_sizes, int n_in,
                              void* d_out, int out_size, void* d_ws, size_t ws_size,
                              hipStream_t stream) {
    const float* x      = (const float*)d_in[0];
    const float* proj_w = (const float*)d_in[1];
    const float* proj_b = (const float*)d_in[2];
    const float* out_w  = (const float*)d_in[3];
    const float* out_b  = (const float*)d_in[4];
    float* out = (float*)d_out;

    // workspace layout (bf16 elements); ctx aliases xs (xs dead after QKV GEMM)
    bf16* xs  = (bf16*)d_ws;                       // 32768*256
    bf16* qkv = xs + (size_t)32768 * 256;          // 32768*768 (V-section unused)
    bf16* vt  = qkv + (size_t)32768 * 768;         // 32*4*64*1024, tiled
    bf16* pwt = vt + (size_t)8388608;              // 768*256
    bf16* owt = pwt + (size_t)768 * 256;           // 256*256
    bf16* ctx = xs;

    k_prep_w     <<<dim3(768),  dim3(256), 0, stream>>>(proj_w, out_w, pwt, owt);
    k_transpose_x<<<dim3(2048), dim3(256), 0, stream>>>(x, xs);
    k_gemm_qkv   <<<dim3(1536), dim3(256), 0, stream>>>(xs, pwt, proj_b, qkv, vt);
    k_attn       <<<dim3(1024), dim3(256), 0, stream>>>(qkv, vt, ctx);
    k_gemm_out   <<<dim3(1024), dim3(256), 0, stream>>>(ctx, owt, out_b, x, out);
}

// Round 6
// 102.778 us; speedup vs baseline: 3.7704x; 1.0560x over previous
//
#include <hip/hip_runtime.h>
#include <hip/hip_bf16.h>

// Problem constants
#define BB  32
#define CC  256
#define NN  1024           // H*W
#define NHH 4
#define DKK 64
#define QD  768            // 3 * NH * DK
// softmax in log2 domain: fold (1/sqrt(64)) * log2(e) into q (weights+bias)
#define QSCALE 0.18033688011112042f

typedef __bf16 bf16;
typedef __bf16 bf16x8 __attribute__((ext_vector_type(8)));
typedef float  f32x4  __attribute__((ext_vector_type(4)));
typedef float  f32x16 __attribute__((ext_vector_type(16)));

typedef __attribute__((address_space(1))) const void g_void;
typedef __attribute__((address_space(3))) void l_void;

// ---------------------------------------------------------------------------
__global__ __launch_bounds__(256) void k_prep_w(const float* __restrict__ proj_w,
                                                const float* __restrict__ out_w,
                                                bf16* __restrict__ pwt,
                                                bf16* __restrict__ owt) {
    int i = blockIdx.x * 256 + threadIdx.x;   // grid covers 768*256
    if (i < QD * CC) {
        int o = i / CC;
        float v = proj_w[i];
        if ((o % 192) < DKK) v *= QSCALE;     // q rows
        pwt[i] = (bf16)v;
    }
    if (i < CC * CC) {
        owt[i] = (bf16)out_w[i];
    }
}

// ---------------------------------------------------------------------------
// x [B][C][N] f32  ->  xs [B*N][C] bf16   (LDS-tiled transpose, 64x64 tiles)
__global__ __launch_bounds__(256) void k_transpose_x(const float* __restrict__ x,
                                                     bf16* __restrict__ xs) {
    int bid = blockIdx.x;                 // B * (C/64) * (N/64) = 2048
    int nt = bid & 15;
    int ct = (bid >> 4) & 3;
    int b  = bid >> 6;
    __shared__ float lds[64][65];
    int t = threadIdx.x;
    const float* xp = x + ((size_t)b * CC + ct * 64) * NN + nt * 64;
#pragma unroll
    for (int rep = 0; rep < 16; ++rep) {
        int idx = rep * 256 + t;
        int c = idx >> 6, n = idx & 63;
        lds[c][n] = xp[(size_t)c * NN + n];          // coalesced over n
    }
    __syncthreads();
    bf16* xo = xs + ((size_t)b * NN + nt * 64) * CC + ct * 64;
#pragma unroll
    for (int rep = 0; rep < 16; ++rep) {
        int idx = rep * 256 + t;
        int c = idx & 63, n = idx >> 6;
        xo[(size_t)n * CC + c] = (bf16)lds[c][n];    // coalesced over c
    }
}

// ---------------------------------------------------------------------------
// QKV GEMM, staged (128x128 tile, BK=32, 2-phase). V columns go straight to
// the 8KB-tiled vt layout [bh][16 kv-tiles][64 d][64 j].
__global__ __launch_bounds__(256, 4) void k_gemm_qkv(const bf16* __restrict__ A,
                                                     const bf16* __restrict__ Bw,
                                                     const float* __restrict__ bias,
                                                     bf16* __restrict__ qkv,
                                                     bf16* __restrict__ vt) {
    // XCD-bijective swizzle: nwg=1536=8*192
    int l = (blockIdx.x & 7) * 192 + (blockIdx.x >> 3);
    int mtile = l / 6, ntile = l % 6;
    int wave = threadIdx.x >> 6, lane = threadIdx.x & 63;
    int wm = wave >> 1, wn = wave & 1;
    int lr = lane & 15, lg = lane >> 4;
    int row0 = mtile * 128, col0 = ntile * 128;

    __shared__ __align__(16) bf16 Abuf[2][4096];   // [128 rows][32 k] 8KB each
    __shared__ __align__(16) bf16 Bbuf[2][4096];

    int srow = lane >> 2, sc = lane & 3;
    int rA0 = wave * 16 + srow, rA1 = (wave + 4) * 16 + srow;
    const bf16* a0 = A + (size_t)(row0 + rA0) * CC + ((sc ^ ((rA0 >> 1) & 3)) * 8);
    const bf16* a1 = A + (size_t)(row0 + rA1) * CC + ((sc ^ ((rA1 >> 1) & 3)) * 8);
    const bf16* b0 = Bw + (size_t)(col0 + rA0) * CC + ((sc ^ ((rA0 >> 1) & 3)) * 8);
    const bf16* b1 = Bw + (size_t)(col0 + rA1) * CC + ((sc ^ ((rA1 >> 1) & 3)) * 8);

#define STAGE(ks, sel)                                                          \
    do {                                                                        \
        __builtin_amdgcn_global_load_lds((g_void*)(a0 + (ks) * 32),             \
            (l_void*)&Abuf[sel][wave * 512], 16, 0, 0);                         \
        __builtin_amdgcn_global_load_lds((g_void*)(a1 + (ks) * 32),             \
            (l_void*)&Abuf[sel][(wave + 4) * 512], 16, 0, 0);                   \
        __builtin_amdgcn_global_load_lds((g_void*)(b0 + (ks) * 32),             \
            (l_void*)&Bbuf[sel][wave * 512], 16, 0, 0);                         \
        __builtin_amdgcn_global_load_lds((g_void*)(b1 + (ks) * 32),             \
            (l_void*)&Bbuf[sel][(wave + 4) * 512], 16, 0, 0);                   \
    } while (0)

    f32x4 acc[4][4] = {};
    STAGE(0, 0);
    asm volatile("s_waitcnt vmcnt(0)" ::: "memory");
    __builtin_amdgcn_s_barrier();

    int cur = 0;
    for (int ks = 0; ks < 8; ++ks) {
        if (ks + 1 < 8) STAGE(ks + 1, cur ^ 1);
        bf16x8 af[4], bfm[4];
#pragma unroll
        for (int mt = 0; mt < 4; ++mt) {
            int row = wm * 64 + mt * 16 + lr;
            af[mt] = *reinterpret_cast<const bf16x8*>(
                &Abuf[cur][row * 32 + ((lg ^ ((row >> 1) & 3)) * 8)]);
        }
#pragma unroll
        for (int nt = 0; nt < 4; ++nt) {
            int row = wn * 64 + nt * 16 + lr;
            bfm[nt] = *reinterpret_cast<const bf16x8*>(
                &Bbuf[cur][row * 32 + ((lg ^ ((row >> 1) & 3)) * 8)]);
        }
#pragma unroll
        for (int mt = 0; mt < 4; ++mt)
#pragma unroll
            for (int nt = 0; nt < 4; ++nt)
                acc[mt][nt] = __builtin_amdgcn_mfma_f32_16x16x32_bf16(
                    af[mt], bfm[nt], acc[mt][nt], 0, 0, 0);
        asm volatile("s_waitcnt vmcnt(0)" ::: "memory");
        __builtin_amdgcn_s_barrier();
        cur ^= 1;
    }
#undef STAGE

    // Epilogue: Q/K -> qkv; V -> vt 8KB tiles [bh][kb64][d][j]
#pragma unroll
    for (int nt = 0; nt < 4; ++nt) {
        int col = col0 + wn * 64 + nt * 16 + lr;
        int sect = col % 192;                      // frag-uniform section type
        int h = col / 192;
        float bv = bias[col];
        if (sect < DKK) bv *= QSCALE;
#pragma unroll
        for (int mt = 0; mt < 4; ++mt) {
            int rowb = row0 + wm * 64 + mt * 16 + lg * 4;
            if (sect < 128) {                      // Q or K -> qkv layout
#pragma unroll
                for (int rr = 0; rr < 4; ++rr)
                    qkv[(size_t)(rowb + rr) * QD + col] =
                        (bf16)(acc[mt][nt][rr] + bv);
            } else {                               // V -> vt tiled layout
                int d = sect - 128;
                int b = rowb >> 10, n = rowb & 1023;
                int kb = n >> 6, j = n & 63;
                unsigned u0, u1;
                asm("v_cvt_pk_bf16_f32 %0, %1, %2" : "=v"(u0)
                    : "v"(acc[mt][nt][0] + bv), "v"(acc[mt][nt][1] + bv));
                asm("v_cvt_pk_bf16_f32 %0, %1, %2" : "=v"(u1)
                    : "v"(acc[mt][nt][2] + bv), "v"(acc[mt][nt][3] + bv));
                *reinterpret_cast<uint2*>(
                    &vt[(((size_t)(b * NHH + h) * 16 + kb) * 64 + d) * 64 + j]) =
                    make_uint2(u0, u1);
            }
        }
    }
}

// ---------------------------------------------------------------------------
// Flash attention: swapped 32x32 MFMA, KVBLK=64, static-unrolled double
// buffer. K tile [64 keys][64 d], V^T tile [64 d][64 keys] -- both 128B rows
// with swizzle swz(r) = (r&7)^((r>>3)&3) on the 8 16B-chunks; linear LDS dest
// + pre-swizzled global source + swizzled read (rule #21).
__global__ __launch_bounds__(256, 4) void k_attn(const bf16* __restrict__ qkv,
                                                 const bf16* __restrict__ vt,
                                                 bf16* __restrict__ ctx) {
    int bid = blockIdx.x;                 // qt(8) x bh(128) = 1024
    int qt = bid >> 7;
    int bh = bid & 127;
    int b  = bh >> 2;
    int h  = bh & 3;
    int wave = threadIdx.x >> 6, lane = threadIdx.x & 63;
    int lq = lane & 31, hi = lane >> 5;
    int q0 = qt * 128 + wave * 32;

    // [K0 | K1 | V0 | V1], 4 x 4096 bf16 (8KB each) = 32 KB total
    __shared__ __align__(16) bf16 smem[16384];

    const bf16* qkb = qkv + (size_t)b * NN * QD;
    const bf16* qrow = qkb + (size_t)(q0 + lq) * QD + h * 192 + 8 * hi;
    bf16x8 qf[4];
#pragma unroll
    for (int dk = 0; dk < 4; ++dk)
        qf[dk] = *reinterpret_cast<const bf16x8*>(qrow + 16 * dk);

    const bf16* kglob = qkb + h * 192 + 64;              // K rows (stride QD)
    const bf16* vtile = vt + (size_t)bh * 16 * 4096;     // V^T 8KB tiles

    // staging: wave w stages rows 16w..16w+15 of both tiles (2 instrs each)
    int srw = lane >> 3, sch = lane & 7;
    int r0 = wave * 16 + srw;
    int g0 = sch ^ srw ^ ((2 * wave) & 3);      // sch ^ swz(r0)
    int g1 = sch ^ srw ^ ((2 * wave + 1) & 3);  // sch ^ swz(r0+8)
    const bf16* kA0 = kglob + (size_t)r0 * QD + g0 * 8;
    const bf16* kA1 = kglob + (size_t)(r0 + 8) * QD + g1 * 8;
    const bf16* vA0 = vtile + r0 * 64 + g0 * 8;
    const bf16* vA1 = vtile + (r0 + 8) * 64 + g1 * 8;

    // read addresses (bf16 units): 4 regs serve all 16 reads via imm offsets
    int swzl = (lq & 7) ^ (lq >> 3);
    int adK[4];
#pragma unroll
    for (int i = 0; i < 4; ++i)
        adK[i] = lq * 64 + (((2 * i) | hi) ^ swzl) * 8;

    f32x16 acc0 = {}, acc1 = {};          // O^T rows d<32 / d>=32, col q=lq
    float m = -1e30f, l = 0.f;

#define STAGE(t, BUF)                                                           \
    do {                                                                        \
        size_t ko = (size_t)(t) * 64 * QD;                                      \
        size_t vo = (size_t)(t) * 4096;                                         \
        __builtin_amdgcn_global_load_lds((g_void*)(kA0 + ko),                   \
            (l_void*)&smem[(BUF) * 4096 + wave * 1024], 16, 0, 0);              \
        __builtin_amdgcn_global_load_lds((g_void*)(kA1 + ko),                   \
            (l_void*)&smem[(BUF) * 4096 + wave * 1024 + 512], 16, 0, 0);        \
        __builtin_amdgcn_global_load_lds((g_void*)(vA0 + vo),                   \
            (l_void*)&smem[8192 + (BUF) * 4096 + wave * 1024], 16, 0, 0);       \
        __builtin_amdgcn_global_load_lds((g_void*)(vA1 + vo),                   \
            (l_void*)&smem[8192 + (BUF) * 4096 + wave * 1024 + 512], 16, 0, 0); \
    } while (0)

#define MAX3(a, b, c) fmaxf(fmaxf((a), (b)), (c))

#define COMPUTE(BUF)                                                            \
    do {                                                                        \
        f32x16 s0 = {}, s1 = {};                                                \
        _Pragma("unroll")                                                       \
        for (int dk = 0; dk < 4; ++dk) {                                        \
            bf16x8 kf0 = *reinterpret_cast<const bf16x8*>(                      \
                &smem[adK[dk] + (BUF) * 4096]);                                 \
            bf16x8 kf1 = *reinterpret_cast<const bf16x8*>(                      \
                &smem[adK[dk] + (BUF) * 4096 + 2048]);                          \
            s0 = __builtin_amdgcn_mfma_f32_32x32x16_bf16(kf0, qf[dk], s0, 0, 0, 0); \
            s1 = __builtin_amdgcn_mfma_f32_32x32x16_bf16(kf1, qf[dk], s1, 0, 0, 0); \
        }                                                                       \
        float x0 = MAX3(s0[0], s0[1], s0[2]);                                   \
        float x1 = MAX3(s0[3], s0[4], s0[5]);                                   \
        float x2 = MAX3(s0[6], s0[7], s0[8]);                                   \
        float x3 = MAX3(s0[9], s0[10], s0[11]);                                 \
        float x4 = MAX3(s0[12], s0[13], s0[14]);                                \
        float x5 = MAX3(s1[0], s1[1], s1[2]);                                   \
        float x6 = MAX3(s1[3], s1[4], s1[5]);                                   \
        float x7 = MAX3(s1[6], s1[7], s1[8]);                                   \
        float x8 = MAX3(s1[9], s1[10], s1[11]);                                 \
        float x9 = MAX3(s1[12], s1[13], s1[14]);                                \
        float xa = fmaxf(s0[15], s1[15]);                                       \
        x0 = MAX3(x0, x1, x2);                                                  \
        x3 = MAX3(x3, x4, x5);                                                  \
        x6 = MAX3(x6, x7, x8);                                                  \
        x9 = MAX3(x9, xa, x0);                                                  \
        x3 = fmaxf(x3, x6);                                                     \
        float pm = fmaxf(x9, x3);                                               \
        {                                                                       \
            float a_ = pm, b_ = pm;                                             \
            asm("v_permlane32_swap_b32 %0, %1" : "+v"(a_), "+v"(b_));           \
            pm = fmaxf(a_, b_);                                                 \
        }                                                                       \
        if (__any(pm > m + 8.f)) {                                              \
            float nm = fmaxf(m, pm);                                            \
            float corr = __builtin_amdgcn_exp2f(m - nm);                        \
            l *= corr; acc0 *= corr; acc1 *= corr; m = nm;                      \
        }                                                                       \
        _Pragma("unroll")                                                       \
        for (int i = 0; i < 16; ++i) {                                          \
            s0[i] = __builtin_amdgcn_exp2f(s0[i] - m);                          \
            s1[i] = __builtin_amdgcn_exp2f(s1[i] - m);                          \
        }                                                                       \
        {                                                                       \
            float l0 = (s0[0] + s0[1]) + (s0[2] + s0[3]);                       \
            float l1 = (s0[4] + s0[5]) + (s0[6] + s0[7]);                       \
            float l2 = (s0[8] + s0[9]) + (s0[10] + s0[11]);                     \
            float l3 = (s0[12] + s0[13]) + (s0[14] + s0[15]);                   \
            float l4 = (s1[0] + s1[1]) + (s1[2] + s1[3]);                       \
            float l5 = (s1[4] + s1[5]) + (s1[6] + s1[7]);                       \
            float l6 = (s1[8] + s1[9]) + (s1[10] + s1[11]);                     \
            float l7 = (s1[12] + s1[13]) + (s1[14] + s1[15]);                   \
            l += ((l0 + l1) + (l2 + l3)) + ((l4 + l5) + (l6 + l7));             \
        }                                                                       \
        union { unsigned u[4]; bf16x8 v; } pu[4];                               \
        _Pragma("unroll")                                                       \
        for (int g = 0; g < 2; ++g) {                                           \
            unsigned w0, w1, w2, w3;                                            \
            asm("v_cvt_pk_bf16_f32 %0, %1, %2" : "=v"(w0)                       \
                : "v"(s0[8 * g + 0]), "v"(s0[8 * g + 1]));                      \
            asm("v_cvt_pk_bf16_f32 %0, %1, %2" : "=v"(w1)                       \
                : "v"(s0[8 * g + 2]), "v"(s0[8 * g + 3]));                      \
            asm("v_cvt_pk_bf16_f32 %0, %1, %2" : "=v"(w2)                       \
                : "v"(s0[8 * g + 4]), "v"(s0[8 * g + 5]));                      \
            asm("v_cvt_pk_bf16_f32 %0, %1, %2" : "=v"(w3)                       \
                : "v"(s0[8 * g + 6]), "v"(s0[8 * g + 7]));                      \
            asm("v_permlane32_swap_b32 %0, %1" : "+v"(w0), "+v"(w2));           \
            asm("v_permlane32_swap_b32 %0, %1" : "+v"(w1), "+v"(w3));           \
            pu[g].u[0] = w0; pu[g].u[1] = w1; pu[g].u[2] = w2; pu[g].u[3] = w3; \
            asm("v_cvt_pk_bf16_f32 %0, %1, %2" : "=v"(w0)                       \
                : "v"(s1[8 * g + 0]), "v"(s1[8 * g + 1]));                      \
            asm("v_cvt_pk_bf16_f32 %0, %1, %2" : "=v"(w1)                       \
                : "v"(s1[8 * g + 2]), "v"(s1[8 * g + 3]));                      \
            asm("v_cvt_pk_bf16_f32 %0, %1, %2" : "=v"(w2)                       \
                : "v"(s1[8 * g + 4]), "v"(s1[8 * g + 5]));                      \
            asm("v_cvt_pk_bf16_f32 %0, %1, %2" : "=v"(w3)                       \
                : "v"(s1[8 * g + 6]), "v"(s1[8 * g + 7]));                      \
            asm("v_permlane32_swap_b32 %0, %1" : "+v"(w0), "+v"(w2));           \
            asm("v_permlane32_swap_b32 %0, %1" : "+v"(w1), "+v"(w3));           \
            pu[2 + g].u[0] = w0; pu[2 + g].u[1] = w1;                           \
            pu[2 + g].u[2] = w2; pu[2 + g].u[3] = w3;                           \
        }                                                                       \
        _Pragma("unroll")                                                       \
        for (int kk = 0; kk < 4; ++kk) {                                        \
            bf16x8 v0_ = *reinterpret_cast<const bf16x8*>(                      \
                &smem[adK[kk] + 8192 + (BUF) * 4096]);                          \
            bf16x8 v1_ = *reinterpret_cast<const bf16x8*>(                      \
                &smem[adK[kk] + 8192 + (BUF) * 4096 + 2048]);                   \
            acc0 = __builtin_amdgcn_mfma_f32_32x32x16_bf16(v0_, pu[kk].v, acc0, 0, 0, 0); \
            acc1 = __builtin_amdgcn_mfma_f32_32x32x16_bf16(v1_, pu[kk].v, acc1, 0, 0, 0); \
        }                                                                       \
    } while (0)

    STAGE(0, 0);
    asm volatile("s_waitcnt vmcnt(0)" ::: "memory");
    __builtin_amdgcn_s_barrier();

    for (int t = 0; t < 16; t += 2) {
        STAGE(t + 1, 1);
        COMPUTE(0);
        asm volatile("s_waitcnt vmcnt(0)" ::: "memory");
        __builtin_amdgcn_s_barrier();
        if (t + 2 < 16) STAGE(t + 2, 0);
        COMPUTE(1);
        asm volatile("s_waitcnt vmcnt(0)" ::: "memory");
        __builtin_amdgcn_s_barrier();
    }
#undef STAGE
#undef COMPUTE

    // combine the two key-half partial sums of l, normalize (in-lane: q=lq)
    {
        float a = l, b2 = l;
        asm("v_permlane32_swap_b32 %0, %1" : "+v"(a), "+v"(b2));
        l = a + b2;
    }
    float inv = 1.0f / l;

    // O^T -> O via per-wave LDS tile (aliased onto smem; loop ended with a
    // barrier so K/V reads are done), pitch 68 bf16, then 16B global stores.
    bf16* tl = &smem[(size_t)wave * 32 * 68];
#pragma unroll
    for (int r = 0; r < 16; ++r) {
        int d = (r & 3) + 8 * (r >> 2) + 4 * hi;
        tl[lq * 68 + d]      = (bf16)(acc0[r] * inv);
        tl[lq * 68 + d + 32] = (bf16)(acc1[r] * inv);
    }
    __syncthreads();
    bf16* cb = ctx + ((size_t)(b * NN + q0)) * 256 + h * 64;
#pragma unroll
    for (int r = 0; r < 4; ++r) {
        int q = 8 * r + (lane >> 3);
        int d0 = (lane & 7) * 8;
        uint2 lo  = *reinterpret_cast<const uint2*>(&tl[q * 68 + d0]);
        uint2 hi2 = *reinterpret_cast<const uint2*>(&tl[q * 68 + d0 + 4]);
        uint4 o4 = make_uint4(lo.x, lo.y, hi2.x, hi2.y);
        *reinterpret_cast<uint4*>(cb + (size_t)q * 256 + d0) = o4;
    }
}

// ---------------------------------------------------------------------------
// Out GEMM + bias + residual, staged (128x64 tile, BK=32), register-direct
// transposed epilogue (float4 along n).
__global__ __launch_bounds__(256, 4) void k_gemm_out(const bf16* __restrict__ A,
                                                     const bf16* __restrict__ Bw,
                                                     const float* __restrict__ bias,
                                                     const float* __restrict__ x,
                                                     float* __restrict__ out) {
    // nwg = 1024 = 8*128
    int l = (blockIdx.x & 7) * 128 + (blockIdx.x >> 3);
    int mtile = l >> 2, ntile = l & 3;
    int wave = threadIdx.x >> 6, lane = threadIdx.x & 63;
    int wm = wave >> 1, wn = wave & 1;
    int lr = lane & 15, lg = lane >> 4;
    int row0 = mtile * 128, col0 = ntile * 64;

    __shared__ __align__(16) bf16 Abuf[2][4096];   // [128][32]
    __shared__ __align__(16) bf16 Bbuf[2][2048];   // [64][32]

    int srow = lane >> 2, sc = lane & 3;
    int rA0 = wave * 16 + srow, rA1 = (wave + 4) * 16 + srow;
    const bf16* a0 = A + (size_t)(row0 + rA0) * CC + ((sc ^ ((rA0 >> 1) & 3)) * 8);
    const bf16* a1 = A + (size_t)(row0 + rA1) * CC + ((sc ^ ((rA1 >> 1) & 3)) * 8);
    const bf16* b0 = Bw + (size_t)(col0 + rA0) * CC + ((sc ^ ((rA0 >> 1) & 3)) * 8);

#define STAGE(ks, sel)                                                          \
    do {                                                                        \
        __builtin_amdgcn_global_load_lds((g_void*)(a0 + (ks) * 32),             \
            (l_void*)&Abuf[sel][wave * 512], 16, 0, 0);                         \
        __builtin_amdgcn_global_load_lds((g_void*)(a1 + (ks) * 32),             \
            (l_void*)&Abuf[sel][(wave + 4) * 512], 16, 0, 0);                   \
        __builtin_amdgcn_global_load_lds((g_void*)(b0 + (ks) * 32),             \
            (l_void*)&Bbuf[sel][wave * 512], 16, 0, 0);                         \
    } while (0)

    f32x4 acc[4][2] = {};
    STAGE(0, 0);
    asm volatile("s_waitcnt vmcnt(0)" ::: "memory");
    __builtin_amdgcn_s_barrier();

    int cur = 0;
    for (int ks = 0; ks < 8; ++ks) {
        if (ks + 1 < 8) STAGE(ks + 1, cur ^ 1);
        bf16x8 af[4], bfm[2];
#pragma unroll
        for (int mt = 0; mt < 4; ++mt) {
            int row = wm * 64 + mt * 16 + lr;
            af[mt] = *reinterpret_cast<const bf16x8*>(
                &Abuf[cur][row * 32 + ((lg ^ ((row >> 1) & 3)) * 8)]);
        }
#pragma unroll
        for (int nt = 0; nt < 2; ++nt) {
            int row = wn * 32 + nt * 16 + lr;
            bfm[nt] = *reinterpret_cast<const bf16x8*>(
                &Bbuf[cur][row * 32 + ((lg ^ ((row >> 1) & 3)) * 8)]);
        }
#pragma unroll
        for (int mt = 0; mt < 4; ++mt)
#pragma unroll
            for (int nt = 0; nt < 2; ++nt)
                acc[mt][nt] = __builtin_amdgcn_mfma_f32_16x16x32_bf16(
                    af[mt], bfm[nt], acc[mt][nt], 0, 0, 0);
        asm volatile("s_waitcnt vmcnt(0)" ::: "memory");
        __builtin_amdgcn_s_barrier();
        cur ^= 1;
    }
#undef STAGE

#pragma unroll
    for (int nt = 0; nt < 2; ++nt) {
        int c = col0 + wn * 32 + nt * 16 + lr;
        float bv = bias[c];
#pragma unroll
        for (int mt = 0; mt < 4; ++mt) {
            int rowb = row0 + wm * 64 + mt * 16 + lg * 4;
            int b = rowb >> 10, n = rowb & 1023;
            size_t o = ((size_t)b * CC + c) * NN + n;
            f32x4 xr = *reinterpret_cast<const f32x4*>(&x[o]);
            f32x4 r = acc[mt][nt] + bv + xr;
            *reinterpret_cast<f32x4*>(&out[o]) = r;
        }
    }
}

// ---------------------------------------------------------------------------
extern "C" void kernel_launch(void* const* d_in, const int* in_sizes, int n_in,
                              void* d_out, int out_size, void* d_ws, size_t ws_size,
                              hipStream_t stream) {
    const float* x      = (const float*)d_in[0];
    const float* proj_w = (const float*)d_in[1];
    const float* proj_b = (const float*)d_in[2];
    const float* out_w  = (const float*)d_in[3];
    const float* out_b  = (const float*)d_in[4];
    float* out = (float*)d_out;

    // workspace layout (bf16 elements); ctx aliases xs (xs dead after QKV GEMM)
    bf16* xs  = (bf16*)d_ws;                       // 32768*256
    bf16* qkv = xs + (size_t)32768 * 256;          // 32768*768 (V-section unused)
    bf16* vt  = qkv + (size_t)32768 * 768;         // 32*4*16*64*64, 8KB tiles
    bf16* pwt = vt + (size_t)8388608;              // 768*256
    bf16* owt = pwt + (size_t)768 * 256;           // 256*256
    bf16* ctx = xs;

    k_prep_w     <<<dim3(768),  dim3(256), 0, stream>>>(proj_w, out_w, pwt, owt);
    k_transpose_x<<<dim3(2048), dim3(256), 0, stream>>>(x, xs);
    k_gemm_qkv   <<<dim3(1536), dim3(256), 0, stream>>>(xs, pwt, proj_b, qkv, vt);
    k_attn       <<<dim3(1024), dim3(256), 0, stream>>>(qkv, vt, ctx);
    k_gemm_out   <<<dim3(1024), dim3(256), 0, stream>>>(ctx, owt, out_b, x, out);
}